// Round 3
// baseline (1000.997 us; speedup 1.0000x reference)
//
#include <hip/hip_runtime.h>
#include <stdint.h>

// Problem constants
#define BB 2
#define SS 2048
#define DD 4096
#define NH 32
#define NKVH 8
#define HD 128
#define QKVN 6144          // (32 + 2*8) * 128
#define MROWS (BB * SS)    // 4096
#define LOG2E 1.4426950408889634f

typedef short bf16x8 __attribute__((ext_vector_type(8)));   // 8 bf16 in 4 VGPRs
typedef float f32x4 __attribute__((ext_vector_type(4)));

__device__ __forceinline__ short f32_bf16(float f) {
  union { float f; unsigned u; } c; c.f = f;
  unsigned r = (c.u + 0x7fffu + ((c.u >> 16) & 1u)) >> 16;   // RNE
  return (short)r;
}
__device__ __forceinline__ float bf16_f32(short h) {
  union { unsigned u; float f; } c; c.u = ((unsigned)(unsigned short)h) << 16;
  return c.f;
}

// async global->LDS, 16B per lane. LDS dest must be wave-uniform base + lane*16.
__device__ __forceinline__ void async16(const void* g, void* l) {
  __builtin_amdgcn_global_load_lds(
      (const __attribute__((address_space(1))) unsigned int*)(uintptr_t)g,
      (__attribute__((address_space(3))) unsigned int*)(uintptr_t)l,
      16, 0, 0);
}

// ---------------------------------------------------------------- cast f32 -> bf16
__global__ __launch_bounds__(256) void cast_bf16_kernel(const float* __restrict__ in,
                                                        short* __restrict__ out, int n4) {
  int i = blockIdx.x * 256 + threadIdx.x;
  if (i >= n4) return;
  float4 v = ((const float4*)in)[i];
  short4 o;
  o.x = f32_bf16(v.x); o.y = f32_bf16(v.y); o.z = f32_bf16(v.z); o.w = f32_bf16(v.w);
  ((short4*)out)[i] = o;
}

// ---------------------------------------------------------------- rope tables
__global__ __launch_bounds__(256) void rope_tables_kernel(float* __restrict__ cosT,
                                                          float* __restrict__ sinT) {
  int idx = blockIdx.x * 256 + threadIdx.x;   // S*64
  if (idx >= SS * 64) return;
  int s = idx >> 6, t = idx & 63;
  float invf = exp2f(-(float)t * (18.931568569324174f / 64.0f));  // log2(500000)/64
  float fr = (float)s * invf;
  float sv, cv;
  sincosf(fr, &sv, &cv);
  cosT[idx] = cv;
  sinT[idx] = sv;
}

// ---------------------------------------------------------------- rope + scatter (Q,K only)
__global__ __launch_bounds__(256) void rope_scatter_kernel(const short* __restrict__ qkv,
    const float* __restrict__ cosT, const float* __restrict__ sinT,
    short* __restrict__ Qb, short* __restrict__ Kb) {
  int idx = blockIdx.x * 256 + threadIdx.x;   // B*S*40*64
  if (idx >= BB * SS * 40 * 64) return;
  int t = idx & 63;
  int hh = (idx >> 6) % 40;
  int bs = (idx >> 6) / 40;
  int s = bs & (SS - 1);
  int b = bs >> 11;
  const short* row = qkv + (long)bs * QKVN + hh * HD;
  float x1 = bf16_f32(row[t]);
  float x2 = bf16_f32(row[t + 64]);
  float c = cosT[(s << 6) + t], sn = sinT[(s << 6) + t];
  float o1 = x1 * c - x2 * sn;
  float o2 = x2 * c + x1 * sn;
  if (hh < 32) {
    const float sc = 0.08838834764831845f;  // 1/sqrt(128), folded into Q
    o1 *= sc; o2 *= sc;
    short* q = Qb + ((long)(b * NH + hh) * SS + s) * HD;
    q[t] = f32_bf16(o1); q[t + 64] = f32_bf16(o2);
  } else {
    short* k = Kb + ((long)(b * NKVH + (hh - 32)) * SS + s) * HD;
    k[t] = f32_bf16(o1); k[t + 64] = f32_bf16(o2);
  }
}

// ---------------------------------------------------------------- V transpose scatter
__global__ __launch_bounds__(256) void v_scatter_kernel(const short* __restrict__ qkv,
                                                        short* __restrict__ Vtb) {
  int bid = blockIdx.x;                 // 512 = B * NKVH * (SS/64)
  int s0 = (bid & 31) << 6;
  int kvh = (bid >> 5) & 7;
  int b = bid >> 8;
  const short* src = qkv + (long)(b * SS + s0) * QKVN + 5120 + kvh * HD;
  short* dst = Vtb + ((long)(b * NKVH + kvh) * HD) * SS + s0;
  int w = threadIdx.x >> 6, l = threadIdx.x & 63;
#pragma unroll
  for (int it = 0; it < 32; ++it) {
    int d = (it << 2) + w;
    dst[(long)d * SS + l] = src[(long)l * QKVN + d];
  }
}

// ---------------------------------------------------------------- GEMM: C[M,N] = A[M,K] @ B[N,K]^T
// XOR-swizzled LDS (T2): 16B slot ^= row&7; global_load_lds dest linear, source
// column pre-swizzled (rule #21). Conflicts 7.55e7 -> ~0 (round 2 verified).
template <int STORE_BF16>
__global__ __launch_bounds__(256) void gemm_bt_kernel(const short* __restrict__ A,
    const short* __restrict__ B, void* __restrict__ Cv, int M, int N, int K) {
  __shared__ __align__(16) short As[128 * 64];
  __shared__ __align__(16) short Bs[128 * 64];
  const int tid = threadIdx.x;
  const int wave = tid >> 6, lane = tid & 63;
  const int quad = lane >> 4, l16 = lane & 15;
  const int m0 = blockIdx.y << 7, n0 = blockIdx.x << 7;
  const int wm = (wave & 1) << 6, wn = (wave >> 1) << 6;
  const int sr = tid >> 3;                       // staged LDS row (0..31, +i*32)
  const int scs = (((tid & 7) ^ (sr & 7)) << 3); // pre-swizzled source column
  const int xr = l16 & 7;                        // read-side row XOR key

  f32x4 acc[4][4];
#pragma unroll
  for (int i = 0; i < 4; i++)
#pragma unroll
    for (int j = 0; j < 4; j++) acc[i][j] = (f32x4){0.f, 0.f, 0.f, 0.f};

  const short* Ag = A + (long)(m0 + sr) * K + scs;
  const short* Bg = B + (long)(n0 + sr) * K + scs;
  short* Asw = &As[sr * 64 + ((tid & 7) << 3)];  // linear dest = base + lane*16
  short* Bsw = &Bs[sr * 64 + ((tid & 7) << 3)];

  for (int k0 = 0; k0 < K; k0 += 64) {
#pragma unroll
    for (int i = 0; i < 4; i++) {
      async16(Ag + (long)(i * 32) * K + k0, Asw + i * 32 * 64);
      async16(Bg + (long)(i * 32) * K + k0, Bsw + i * 32 * 64);
    }
    __syncthreads();
#pragma unroll
    for (int kk = 0; kk < 64; kk += 32) {
      const int slot = ((quad + (kk >> 3)) ^ xr) << 3;   // swizzled 8-elem slot
      bf16x8 a[4], b[4];
#pragma unroll
      for (int i = 0; i < 4; i++)
        a[i] = *(const bf16x8*)&As[(wm + i * 16 + l16) * 64 + slot];
#pragma unroll
      for (int j = 0; j < 4; j++)
        b[j] = *(const bf16x8*)&Bs[(wn + j * 16 + l16) * 64 + slot];
#pragma unroll
      for (int i = 0; i < 4; i++)
#pragma unroll
        for (int j = 0; j < 4; j++)
          acc[i][j] = __builtin_amdgcn_mfma_f32_16x16x32_bf16(a[i], b[j], acc[i][j], 0, 0, 0);
    }
    __syncthreads();
  }
#pragma unroll
  for (int i = 0; i < 4; i++)
#pragma unroll
    for (int j = 0; j < 4; j++)
#pragma unroll
      for (int r = 0; r < 4; r++) {
        long row = m0 + wm + i * 16 + quad * 4 + r;
        long col = n0 + wn + j * 16 + l16;
        if (STORE_BF16)
          ((short*)Cv)[row * N + col] = f32_bf16(acc[i][j][r]);
        else
          ((float*)Cv)[row * N + col] = acc[i][j][r];
      }
}

// ---------------------------------------------------------------- flash attention v6
// v6: LATENCY FIX. v5 was latency-bound (~19K cy/tile vs ~600 cy of work):
// V fragments were loaded one-at-a-time inside the PV loop (16 serial ~600cy
// load->use chains) and K in 4 wait-separated batches; meanwhile the default
// block->XCD round-robin scattered the 32 blocks sharing one (b,kvh) across all
// 8 XCDs (16MB KV working set vs 4MB L2 -> thrash, FETCH 85MB = 5x re-read).
// Now: (a) K tile in kf[16] regs, prefetched for t+1 during PV of t; V tile
// batched into vf[16] issued right after QK (latency hidden under exp+P, ~300cy);
// (b) 1-D grid decoded so all 32 blocks of one (b,kvh) share bid%8 -> same XCD
// -> 2MB KV per XCD L2-resident. VGPR headroom is free: grid-limited 2 blocks/CU.
#define PSS 72   // P LDS row stride (elements): 144B, 16B-multiple, pad vs conflicts

__global__ __launch_bounds__(256, 2) void flash_attn_kernel(const short* __restrict__ Q,
    const short* __restrict__ Kt, const short* __restrict__ Vt, short* __restrict__ O) {
  __shared__ __align__(16) short Ps[4][32 * PSS];
  const int tid = threadIdx.x;
  const int wave = tid >> 6, lane = tid & 63;
  const int quad = lane >> 4, l16 = lane & 15;

  // XCD co-location decode: 512 blocks; blocks sharing (b,kvh) share bid%8.
  const int flat = blockIdx.x;
  const int xcd = flat & 7;
  const int kk_ = flat >> 3;          // 0..63
  const int gsel = kk_ >> 5;          // 0..1
  const int jj = kk_ & 31;            // 0..31
  const int g = xcd * 2 + gsel;       // 0..15 = (b,kvh) group
  const int b = g >> 3, kvh = g & 7;
  const int h = (kvh << 2) + (jj >> 3);
  const int qb0 = jj & 7;

  const short* Kb = Kt + (long)(b * NKVH + kvh) * SS * HD;
  const short* Vb = Vt + (long)(b * NKVH + kvh) * HD * SS;
  short* Pw = &Ps[wave][0];

  // Two causal-complementary Q-groups per wave: exactly 33 key-tiles per wave.
#pragma unroll 1
  for (int half = 0; half < 2; half++) {
    const int qb = half ? (15 - qb0) : qb0;
    const int w = half ? (3 - wave) : wave;
    const int q0w = (qb << 7) + (w << 5);

    const short* Qw = Q + ((long)(b * NH + h) * SS + q0w) * HD;
    bf16x8 qf[2][4];
#pragma unroll
    for (int i = 0; i < 2; i++)
#pragma unroll
      for (int kk = 0; kk < 4; kk++)
        qf[i][kk] = *(const bf16x8*)&Qw[(i * 16 + l16) * HD + kk * 32 + quad * 8];

    f32x4 oacc[2][8];
#pragma unroll
    for (int i = 0; i < 2; i++)
#pragma unroll
      for (int jo = 0; jo < 8; jo++) oacc[i][jo] = (f32x4){0.f, 0.f, 0.f, 0.f};
    float l_i[2][4];
#pragma unroll
    for (int i = 0; i < 2; i++)
#pragma unroll
      for (int r = 0; r < 4; r++) l_i[i][r] = 0.f;

    const int nfull = q0w >> 6;            // last tile index (inclusive)

    // K prologue: tile 0 fragments into registers
    bf16x8 kf[16];
#pragma unroll
    for (int kk = 0; kk < 4; kk++)
#pragma unroll
      for (int j = 0; j < 4; j++)
        kf[kk * 4 + j] = *(const bf16x8*)&Kb[(long)(j * 16 + l16) * HD + kk * 32 + quad * 8];

#pragma unroll 1
    for (int t = 0; t <= nfull; t++) {
      const int j0 = t << 6;
      const bool last = (t == nfull);

      // scores S = Q K^T from register-resident kf
      f32x4 sc[2][4];
#pragma unroll
      for (int i = 0; i < 2; i++)
#pragma unroll
        for (int j = 0; j < 4; j++) sc[i][j] = (f32x4){0.f, 0.f, 0.f, 0.f};
      __builtin_amdgcn_s_setprio(1);
#pragma unroll
      for (int kk = 0; kk < 4; kk++)
#pragma unroll
        for (int i = 0; i < 2; i++)
#pragma unroll
          for (int j = 0; j < 4; j++)
            sc[i][j] = __builtin_amdgcn_mfma_f32_16x16x32_bf16(qf[i][kk], kf[kk * 4 + j],
                                                               sc[i][j], 0, 0, 0);
      __builtin_amdgcn_s_setprio(0);

      // issue the full V tile now: latency hides under mask/exp/P-transpose
      bf16x8 vf[16];
#pragma unroll
      for (int kv = 0; kv < 2; kv++)
#pragma unroll
        for (int jo = 0; jo < 8; jo++)
          vf[kv * 8 + jo] =
              *(const bf16x8*)&Vb[(long)(jo * 16 + l16) * SS + j0 + kv * 32 + quad * 8];

      if (last) {
#pragma unroll
        for (int i = 0; i < 2; i++)
#pragma unroll
          for (int r = 0; r < 4; r++) {
            int row = q0w + i * 16 + quad * 4 + r;
#pragma unroll
            for (int j = 0; j < 4; j++) {
              int col = j0 + j * 16 + l16;
              if (col > row) sc[i][j][r] = -3.0e38f;
            }
          }
      }

      // p = exp(s); per-lane row-sum partials (max-free)
#pragma unroll
      for (int i = 0; i < 2; i++)
#pragma unroll
        for (int r = 0; r < 4; r++) {
          float ps = 0.f;
#pragma unroll
          for (int j = 0; j < 4; j++) {
            float p = __builtin_amdgcn_exp2f(sc[i][j][r] * LOG2E);
            sc[i][j][r] = p;
            ps += p;
          }
          l_i[i][r] += ps;
        }

      // P: C-layout -> per-wave LDS -> A-layout
#pragma unroll
      for (int i = 0; i < 2; i++)
#pragma unroll
        for (int j = 0; j < 4; j++)
#pragma unroll
          for (int r = 0; r < 4; r++)
            Pw[(i * 16 + quad * 4 + r) * PSS + j * 16 + l16] = f32_bf16(sc[i][j][r]);
      asm volatile("s_waitcnt lgkmcnt(0)" ::: "memory");

      // prefetch next K tile while PV runs (kf regs are dead after QK)
      if (!last) {
        const int jn = j0 + 64;
#pragma unroll
        for (int kk = 0; kk < 4; kk++)
#pragma unroll
          for (int j = 0; j < 4; j++)
            kf[kk * 4 + j] =
                *(const bf16x8*)&Kb[(long)(jn + j * 16 + l16) * HD + kk * 32 + quad * 8];
      }

      // O += P V from register-resident vf
      bf16x8 ap[2][2];
#pragma unroll
      for (int kv = 0; kv < 2; kv++) {
        ap[kv][0] = *(const bf16x8*)&Pw[l16 * PSS + kv * 32 + quad * 8];
        ap[kv][1] = *(const bf16x8*)&Pw[(16 + l16) * PSS + kv * 32 + quad * 8];
      }
      __builtin_amdgcn_s_setprio(1);
#pragma unroll
      for (int kv = 0; kv < 2; kv++)
#pragma unroll
        for (int jo = 0; jo < 8; jo++) {
          oacc[0][jo] = __builtin_amdgcn_mfma_f32_16x16x32_bf16(ap[kv][0], vf[kv * 8 + jo],
                                                                oacc[0][jo], 0, 0, 0);
          oacc[1][jo] = __builtin_amdgcn_mfma_f32_16x16x32_bf16(ap[kv][1], vf[kv * 8 + jo],
                                                                oacc[1][jo], 0, 0, 0);
        }
      __builtin_amdgcn_s_setprio(0);
    }

    // epilogue: reduce l across the 16 lanes of each quad (once), store
    short* Ob = O + (long)(b * SS + q0w) * DD + h * HD;
#pragma unroll
    for (int i = 0; i < 2; i++)
#pragma unroll
      for (int r = 0; r < 4; r++) {
        float s = l_i[i][r];
        s += __shfl_xor(s, 1, 64);
        s += __shfl_xor(s, 2, 64);
        s += __shfl_xor(s, 4, 64);
        s += __shfl_xor(s, 8, 64);
        float inv = 1.0f / s;
        int row = i * 16 + quad * 4 + r;
#pragma unroll
        for (int jo = 0; jo < 8; jo++)
          Ob[(long)row * DD + jo * 16 + l16] = f32_bf16(oacc[i][jo][r] * inv);
      }
  }
}

// ---------------------------------------------------------------- launch
extern "C" void kernel_launch(void* const* d_in, const int* in_sizes, int n_in,
                              void* d_out, int out_size, void* d_ws, size_t ws_size,
                              hipStream_t stream) {
  (void)in_sizes; (void)n_in; (void)out_size; (void)ws_size;
  const float* x    = (const float*)d_in[0];
  const float* Wqkv = (const float*)d_in[1];
  const float* Wo   = (const float*)d_in[2];
  char* ws = (char*)d_ws;
  short* xb    = (short*)(ws + 0);            // x bf16 (33.5MB); reused as attn out
  short* wqkvb = (short*)(ws + 33554432);     // Wqkv bf16 (50.3MB)
  short* qkvb  = (short*)(ws + 83886080);     // qkv (50.3MB); reused as Wo bf16
  short* Qb    = (short*)(ws + 134217728);    // 33.5MB
  short* Kb    = (short*)(ws + 167772160);    // 8.4MB
  short* Vtb   = (short*)(ws + 176160768);    // 8.4MB
  float* cosT  = (float*)(ws + 184549376);    // 0.5MB
  float* sinT  = (float*)(ws + 185073664);    // 0.5MB
  short* wob   = qkvb;
  short* attnb = xb;

  cast_bf16_kernel<<<16384, 256, 0, stream>>>(x, xb, 4194304);
  cast_bf16_kernel<<<24576, 256, 0, stream>>>(Wqkv, wqkvb, 6291456);
  gemm_bt_kernel<1><<<dim3(QKVN / 128, MROWS / 128), 256, 0, stream>>>(
      xb, wqkvb, (void*)qkvb, MROWS, QKVN, DD);
  rope_tables_kernel<<<512, 256, 0, stream>>>(cosT, sinT);
  rope_scatter_kernel<<<40960, 256, 0, stream>>>(qkvb, cosT, sinT, Qb, Kb);
  v_scatter_kernel<<<512, 256, 0, stream>>>(qkvb, Vtb);
  cast_bf16_kernel<<<16384, 256, 0, stream>>>(Wo, wob, 4194304);   // overwrites qkvb (dead)
  flash_attn_kernel<<<512, 256, 0, stream>>>(Qb, Kb, Vtb, attnb);
  gemm_bt_kernel<0><<<dim3(DD / 128, MROWS / 128), 256, 0, stream>>>(
      attnb, wob, d_out, MROWS, DD, DD);
}

// Round 4
// 937.706 us; speedup vs baseline: 1.0675x; 1.0675x over previous
//
#include <hip/hip_runtime.h>
#include <stdint.h>

// Problem constants
#define BB 2
#define SS 2048
#define DD 4096
#define NH 32
#define NKVH 8
#define HD 128
#define QKVN 6144          // (32 + 2*8) * 128
#define MROWS (BB * SS)    // 4096
#define LOG2E 1.4426950408889634f

typedef short bf16x8 __attribute__((ext_vector_type(8)));   // 8 bf16 in 4 VGPRs
typedef float f32x4 __attribute__((ext_vector_type(4)));

__device__ __forceinline__ short f32_bf16(float f) {
  union { float f; unsigned u; } c; c.f = f;
  unsigned r = (c.u + 0x7fffu + ((c.u >> 16) & 1u)) >> 16;   // RNE
  return (short)r;
}
__device__ __forceinline__ float bf16_f32(short h) {
  union { unsigned u; float f; } c; c.u = ((unsigned)(unsigned short)h) << 16;
  return c.f;
}

// async global->LDS, 16B per lane. LDS dest must be wave-uniform base + lane*16.
__device__ __forceinline__ void async16(const void* g, void* l) {
  __builtin_amdgcn_global_load_lds(
      (const __attribute__((address_space(1))) unsigned int*)(uintptr_t)g,
      (__attribute__((address_space(3))) unsigned int*)(uintptr_t)l,
      16, 0, 0);
}

// ---------------------------------------------------------------- cast f32 -> bf16
__global__ __launch_bounds__(256) void cast_bf16_kernel(const float* __restrict__ in,
                                                        short* __restrict__ out, int n4) {
  int i = blockIdx.x * 256 + threadIdx.x;
  if (i >= n4) return;
  float4 v = ((const float4*)in)[i];
  short4 o;
  o.x = f32_bf16(v.x); o.y = f32_bf16(v.y); o.z = f32_bf16(v.z); o.w = f32_bf16(v.w);
  ((short4*)out)[i] = o;
}

// ---------------------------------------------------------------- rope tables
__global__ __launch_bounds__(256) void rope_tables_kernel(float* __restrict__ cosT,
                                                          float* __restrict__ sinT) {
  int idx = blockIdx.x * 256 + threadIdx.x;   // S*64
  if (idx >= SS * 64) return;
  int s = idx >> 6, t = idx & 63;
  float invf = exp2f(-(float)t * (18.931568569324174f / 64.0f));  // log2(500000)/64
  float fr = (float)s * invf;
  float sv, cv;
  sincosf(fr, &sv, &cv);
  cosT[idx] = cv;
  sinT[idx] = sv;
}

// ---------------------------------------------------------------- rope + scatter (Q,K only)
__global__ __launch_bounds__(256) void rope_scatter_kernel(const short* __restrict__ qkv,
    const float* __restrict__ cosT, const float* __restrict__ sinT,
    short* __restrict__ Qb, short* __restrict__ Kb) {
  int idx = blockIdx.x * 256 + threadIdx.x;   // B*S*40*64
  if (idx >= BB * SS * 40 * 64) return;
  int t = idx & 63;
  int hh = (idx >> 6) % 40;
  int bs = (idx >> 6) / 40;
  int s = bs & (SS - 1);
  int b = bs >> 11;
  const short* row = qkv + (long)bs * QKVN + hh * HD;
  float x1 = bf16_f32(row[t]);
  float x2 = bf16_f32(row[t + 64]);
  float c = cosT[(s << 6) + t], sn = sinT[(s << 6) + t];
  float o1 = x1 * c - x2 * sn;
  float o2 = x2 * c + x1 * sn;
  if (hh < 32) {
    const float sc = 0.08838834764831845f;  // 1/sqrt(128), folded into Q
    o1 *= sc; o2 *= sc;
    short* q = Qb + ((long)(b * NH + hh) * SS + s) * HD;
    q[t] = f32_bf16(o1); q[t + 64] = f32_bf16(o2);
  } else {
    short* k = Kb + ((long)(b * NKVH + (hh - 32)) * SS + s) * HD;
    k[t] = f32_bf16(o1); k[t + 64] = f32_bf16(o2);
  }
}

// ---------------------------------------------------------------- V transpose scatter
__global__ __launch_bounds__(256) void v_scatter_kernel(const short* __restrict__ qkv,
                                                        short* __restrict__ Vtb) {
  int bid = blockIdx.x;                 // 512 = B * NKVH * (SS/64)
  int s0 = (bid & 31) << 6;
  int kvh = (bid >> 5) & 7;
  int b = bid >> 8;
  const short* src = qkv + (long)(b * SS + s0) * QKVN + 5120 + kvh * HD;
  short* dst = Vtb + ((long)(b * NKVH + kvh) * HD) * SS + s0;
  int w = threadIdx.x >> 6, l = threadIdx.x & 63;
#pragma unroll
  for (int it = 0; it < 32; ++it) {
    int d = (it << 2) + w;
    dst[(long)d * SS + l] = src[(long)l * QKVN + d];
  }
}

// ---------------------------------------------------------------- GEMM: C[M,N] = A[M,K] @ B[N,K]^T
// XOR-swizzled LDS (T2): 16B slot ^= row&7; global_load_lds dest linear, source
// column pre-swizzled (rule #21). Conflicts 7.55e7 -> ~0 (round 2 verified).
template <int STORE_BF16>
__global__ __launch_bounds__(256) void gemm_bt_kernel(const short* __restrict__ A,
    const short* __restrict__ B, void* __restrict__ Cv, int M, int N, int K) {
  __shared__ __align__(16) short As[128 * 64];
  __shared__ __align__(16) short Bs[128 * 64];
  const int tid = threadIdx.x;
  const int wave = tid >> 6, lane = tid & 63;
  const int quad = lane >> 4, l16 = lane & 15;
  const int m0 = blockIdx.y << 7, n0 = blockIdx.x << 7;
  const int wm = (wave & 1) << 6, wn = (wave >> 1) << 6;
  const int sr = tid >> 3;                       // staged LDS row (0..31, +i*32)
  const int scs = (((tid & 7) ^ (sr & 7)) << 3); // pre-swizzled source column
  const int xr = l16 & 7;                        // read-side row XOR key

  f32x4 acc[4][4];
#pragma unroll
  for (int i = 0; i < 4; i++)
#pragma unroll
    for (int j = 0; j < 4; j++) acc[i][j] = (f32x4){0.f, 0.f, 0.f, 0.f};

  const short* Ag = A + (long)(m0 + sr) * K + scs;
  const short* Bg = B + (long)(n0 + sr) * K + scs;
  short* Asw = &As[sr * 64 + ((tid & 7) << 3)];  // linear dest = base + lane*16
  short* Bsw = &Bs[sr * 64 + ((tid & 7) << 3)];

  for (int k0 = 0; k0 < K; k0 += 64) {
#pragma unroll
    for (int i = 0; i < 4; i++) {
      async16(Ag + (long)(i * 32) * K + k0, Asw + i * 32 * 64);
      async16(Bg + (long)(i * 32) * K + k0, Bsw + i * 32 * 64);
    }
    __syncthreads();
#pragma unroll
    for (int kk = 0; kk < 64; kk += 32) {
      const int slot = ((quad + (kk >> 3)) ^ xr) << 3;   // swizzled 8-elem slot
      bf16x8 a[4], b[4];
#pragma unroll
      for (int i = 0; i < 4; i++)
        a[i] = *(const bf16x8*)&As[(wm + i * 16 + l16) * 64 + slot];
#pragma unroll
      for (int j = 0; j < 4; j++)
        b[j] = *(const bf16x8*)&Bs[(wn + j * 16 + l16) * 64 + slot];
#pragma unroll
      for (int i = 0; i < 4; i++)
#pragma unroll
        for (int j = 0; j < 4; j++)
          acc[i][j] = __builtin_amdgcn_mfma_f32_16x16x32_bf16(a[i], b[j], acc[i][j], 0, 0, 0);
    }
    __syncthreads();
  }
#pragma unroll
  for (int i = 0; i < 4; i++)
#pragma unroll
    for (int j = 0; j < 4; j++)
#pragma unroll
      for (int r = 0; r < 4; r++) {
        long row = m0 + wm + i * 16 + quad * 4 + r;
        long col = n0 + wn + j * 16 + l16;
        if (STORE_BF16)
          ((short*)Cv)[row * N + col] = f32_bf16(acc[i][j][r]);
        else
          ((float*)Cv)[row * N + col] = acc[i][j][r];
      }
}

// ---------------------------------------------------------------- flash attention v7
// v7: v6's latency fix with the register budget done right. v6 spilled (peak live
// ~272 VGPR: kf+vf+qf+oacc+sc+ap > 256 cap -> 460MB scratch writes, 370us).
// Changes vs v6:
//  - NO cross-tile K prefetch (that was +64 live across PV). Current tile's 16 K
//    fragments load in ONE back-to-back batch before QK (1 exposed latency/tile
//    vs v5's 4); kf dies during QK so it never overlaps V.
//  - V split in two 8-frag batches: vfa issued right after QK (hides under
//    mask/exp/P-write), vfb issued before PV0 (hides under PV0's 16 MFMAs).
//    Peak live ~190 VGPR -> no spill at (256,2).
//  - XCD co-location decode kept (round 3: FETCH 85->74MB, confirmed).
#define PSS 72   // P LDS row stride (elements): 144B, 16B-multiple, pad vs conflicts

__global__ __launch_bounds__(256, 2) void flash_attn_kernel(const short* __restrict__ Q,
    const short* __restrict__ Kt, const short* __restrict__ Vt, short* __restrict__ O) {
  __shared__ __align__(16) short Ps[4][32 * PSS];
  const int tid = threadIdx.x;
  const int wave = tid >> 6, lane = tid & 63;
  const int quad = lane >> 4, l16 = lane & 15;

  // XCD co-location decode: 512 blocks; blocks sharing (b,kvh) share bid%8.
  const int flat = blockIdx.x;
  const int xcd = flat & 7;
  const int kk_ = flat >> 3;          // 0..63
  const int gsel = kk_ >> 5;          // 0..1
  const int jj = kk_ & 31;            // 0..31
  const int g = xcd * 2 + gsel;       // 0..15 = (b,kvh) group
  const int b = g >> 3, kvh = g & 7;
  const int h = (kvh << 2) + (jj >> 3);
  const int qb0 = jj & 7;

  const short* Kb = Kt + (long)(b * NKVH + kvh) * SS * HD;
  const short* Vb = Vt + (long)(b * NKVH + kvh) * HD * SS;
  short* Pw = &Ps[wave][0];

  // Two causal-complementary Q-groups per wave: exactly 33 key-tiles per wave.
#pragma unroll 1
  for (int half = 0; half < 2; half++) {
    const int qb = half ? (15 - qb0) : qb0;
    const int w = half ? (3 - wave) : wave;
    const int q0w = (qb << 7) + (w << 5);

    const short* Qw = Q + ((long)(b * NH + h) * SS + q0w) * HD;
    bf16x8 qf[2][4];
#pragma unroll
    for (int i = 0; i < 2; i++)
#pragma unroll
      for (int kk = 0; kk < 4; kk++)
        qf[i][kk] = *(const bf16x8*)&Qw[(i * 16 + l16) * HD + kk * 32 + quad * 8];

    f32x4 oacc[2][8];
#pragma unroll
    for (int i = 0; i < 2; i++)
#pragma unroll
      for (int jo = 0; jo < 8; jo++) oacc[i][jo] = (f32x4){0.f, 0.f, 0.f, 0.f};
    float l_i[2][4];
#pragma unroll
    for (int i = 0; i < 2; i++)
#pragma unroll
      for (int r = 0; r < 4; r++) l_i[i][r] = 0.f;

    const int nfull = q0w >> 6;            // last tile index (inclusive)

#pragma unroll 1
    for (int t = 0; t <= nfull; t++) {
      const int j0 = t << 6;
      const bool last = (t == nfull);

      // K tile: all 16 fragments issued back-to-back (one latency exposure)
      bf16x8 kf[16];
#pragma unroll
      for (int kk = 0; kk < 4; kk++)
#pragma unroll
        for (int j = 0; j < 4; j++)
          kf[kk * 4 + j] =
              *(const bf16x8*)&Kb[(long)(j0 + j * 16 + l16) * HD + kk * 32 + quad * 8];

      // scores S = Q K^T
      f32x4 sc[2][4];
#pragma unroll
      for (int i = 0; i < 2; i++)
#pragma unroll
        for (int j = 0; j < 4; j++) sc[i][j] = (f32x4){0.f, 0.f, 0.f, 0.f};
      __builtin_amdgcn_s_setprio(1);
#pragma unroll
      for (int kk = 0; kk < 4; kk++)
#pragma unroll
        for (int i = 0; i < 2; i++)
#pragma unroll
          for (int j = 0; j < 4; j++)
            sc[i][j] = __builtin_amdgcn_mfma_f32_16x16x32_bf16(qf[i][kk], kf[kk * 4 + j],
                                                               sc[i][j], 0, 0, 0);
      __builtin_amdgcn_s_setprio(0);

      // V first half (kv=0): latency hides under mask/exp/P-write
      bf16x8 vfa[8];
#pragma unroll
      for (int jo = 0; jo < 8; jo++)
        vfa[jo] = *(const bf16x8*)&Vb[(long)(jo * 16 + l16) * SS + j0 + quad * 8];

      if (last) {
#pragma unroll
        for (int i = 0; i < 2; i++)
#pragma unroll
          for (int r = 0; r < 4; r++) {
            int row = q0w + i * 16 + quad * 4 + r;
#pragma unroll
            for (int j = 0; j < 4; j++) {
              int col = j0 + j * 16 + l16;
              if (col > row) sc[i][j][r] = -3.0e38f;
            }
          }
      }

      // p = exp(s); per-lane row-sum partials (max-free)
#pragma unroll
      for (int i = 0; i < 2; i++)
#pragma unroll
        for (int r = 0; r < 4; r++) {
          float ps = 0.f;
#pragma unroll
          for (int j = 0; j < 4; j++) {
            float p = __builtin_amdgcn_exp2f(sc[i][j][r] * LOG2E);
            sc[i][j][r] = p;
            ps += p;
          }
          l_i[i][r] += ps;
        }

      // P: C-layout -> per-wave LDS -> A-layout
#pragma unroll
      for (int i = 0; i < 2; i++)
#pragma unroll
        for (int j = 0; j < 4; j++)
#pragma unroll
          for (int r = 0; r < 4; r++)
            Pw[(i * 16 + quad * 4 + r) * PSS + j * 16 + l16] = f32_bf16(sc[i][j][r]);
      asm volatile("s_waitcnt lgkmcnt(0)" ::: "memory");

      bf16x8 ap[2][2];
#pragma unroll
      for (int kv = 0; kv < 2; kv++) {
        ap[kv][0] = *(const bf16x8*)&Pw[l16 * PSS + kv * 32 + quad * 8];
        ap[kv][1] = *(const bf16x8*)&Pw[(16 + l16) * PSS + kv * 32 + quad * 8];
      }

      // V second half (kv=1): latency hides under PV0's 16 MFMAs
      bf16x8 vfb[8];
#pragma unroll
      for (int jo = 0; jo < 8; jo++)
        vfb[jo] = *(const bf16x8*)&Vb[(long)(jo * 16 + l16) * SS + j0 + 32 + quad * 8];

      __builtin_amdgcn_s_setprio(1);
#pragma unroll
      for (int jo = 0; jo < 8; jo++) {
        oacc[0][jo] = __builtin_amdgcn_mfma_f32_16x16x32_bf16(ap[0][0], vfa[jo],
                                                              oacc[0][jo], 0, 0, 0);
        oacc[1][jo] = __builtin_amdgcn_mfma_f32_16x16x32_bf16(ap[0][1], vfa[jo],
                                                              oacc[1][jo], 0, 0, 0);
      }
#pragma unroll
      for (int jo = 0; jo < 8; jo++) {
        oacc[0][jo] = __builtin_amdgcn_mfma_f32_16x16x32_bf16(ap[1][0], vfb[jo],
                                                              oacc[0][jo], 0, 0, 0);
        oacc[1][jo] = __builtin_amdgcn_mfma_f32_16x16x32_bf16(ap[1][1], vfb[jo],
                                                              oacc[1][jo], 0, 0, 0);
      }
      __builtin_amdgcn_s_setprio(0);
    }

    // epilogue: reduce l across the 16 lanes of each quad (once), store
    short* Ob = O + (long)(b * SS + q0w) * DD + h * HD;
#pragma unroll
    for (int i = 0; i < 2; i++)
#pragma unroll
      for (int r = 0; r < 4; r++) {
        float s = l_i[i][r];
        s += __shfl_xor(s, 1, 64);
        s += __shfl_xor(s, 2, 64);
        s += __shfl_xor(s, 4, 64);
        s += __shfl_xor(s, 8, 64);
        float inv = 1.0f / s;
        int row = i * 16 + quad * 4 + r;
#pragma unroll
        for (int jo = 0; jo < 8; jo++)
          Ob[(long)row * DD + jo * 16 + l16] = f32_bf16(oacc[i][jo][r] * inv);
      }
  }
}

// ---------------------------------------------------------------- launch
extern "C" void kernel_launch(void* const* d_in, const int* in_sizes, int n_in,
                              void* d_out, int out_size, void* d_ws, size_t ws_size,
                              hipStream_t stream) {
  (void)in_sizes; (void)n_in; (void)out_size; (void)ws_size;
  const float* x    = (const float*)d_in[0];
  const float* Wqkv = (const float*)d_in[1];
  const float* Wo   = (const float*)d_in[2];
  char* ws = (char*)d_ws;
  short* xb    = (short*)(ws + 0);            // x bf16 (33.5MB); reused as attn out
  short* wqkvb = (short*)(ws + 33554432);     // Wqkv bf16 (50.3MB)
  short* qkvb  = (short*)(ws + 83886080);     // qkv (50.3MB); reused as Wo bf16
  short* Qb    = (short*)(ws + 134217728);    // 33.5MB
  short* Kb    = (short*)(ws + 167772160);    // 8.4MB
  short* Vtb   = (short*)(ws + 176160768);    // 8.4MB
  float* cosT  = (float*)(ws + 184549376);    // 0.5MB
  float* sinT  = (float*)(ws + 185073664);    // 0.5MB
  short* wob   = qkvb;
  short* attnb = xb;

  cast_bf16_kernel<<<16384, 256, 0, stream>>>(x, xb, 4194304);
  cast_bf16_kernel<<<24576, 256, 0, stream>>>(Wqkv, wqkvb, 6291456);
  gemm_bt_kernel<1><<<dim3(QKVN / 128, MROWS / 128), 256, 0, stream>>>(
      xb, wqkvb, (void*)qkvb, MROWS, QKVN, DD);
  rope_tables_kernel<<<512, 256, 0, stream>>>(cosT, sinT);
  rope_scatter_kernel<<<40960, 256, 0, stream>>>(qkvb, cosT, sinT, Qb, Kb);
  v_scatter_kernel<<<512, 256, 0, stream>>>(qkvb, Vtb);
  cast_bf16_kernel<<<16384, 256, 0, stream>>>(Wo, wob, 4194304);   // overwrites qkvb (dead)
  flash_attn_kernel<<<512, 256, 0, stream>>>(Qb, Kb, Vtb, attnb);
  gemm_bt_kernel<0><<<dim3(DD / 128, MROWS / 128), 256, 0, stream>>>(
      attnb, wob, d_out, MROWS, DD, DD);
}

// Round 6
// 917.556 us; speedup vs baseline: 1.0909x; 1.0220x over previous
//
#include <hip/hip_runtime.h>
#include <stdint.h>

// Problem constants
#define BB 2
#define SS 2048
#define DD 4096
#define NH 32
#define NKVH 8
#define HD 128
#define QKVN 6144          // (32 + 2*8) * 128
#define MROWS (BB * SS)    // 4096
#define LOG2E 1.4426950408889634f

typedef short bf16x8 __attribute__((ext_vector_type(8)));   // 8 bf16 in 4 VGPRs
typedef float f32x4 __attribute__((ext_vector_type(4)));

__device__ __forceinline__ short f32_bf16(float f) {
  union { float f; unsigned u; } c; c.f = f;
  unsigned r = (c.u + 0x7fffu + ((c.u >> 16) & 1u)) >> 16;   // RNE
  return (short)r;
}
__device__ __forceinline__ float bf16_f32(short h) {
  union { unsigned u; float f; } c; c.u = ((unsigned)(unsigned short)h) << 16;
  return c.f;
}

// async global->LDS, 16B per lane. LDS dest must be wave-uniform base + lane*16.
__device__ __forceinline__ void async16(const void* g, void* l) {
  __builtin_amdgcn_global_load_lds(
      (const __attribute__((address_space(1))) unsigned int*)(uintptr_t)g,
      (__attribute__((address_space(3))) unsigned int*)(uintptr_t)l,
      16, 0, 0);
}

// ---------------------------------------------------------------- cast f32 -> bf16
__global__ __launch_bounds__(256) void cast_bf16_kernel(const float* __restrict__ in,
                                                        short* __restrict__ out, int n4) {
  int i = blockIdx.x * 256 + threadIdx.x;
  if (i >= n4) return;
  float4 v = ((const float4*)in)[i];
  short4 o;
  o.x = f32_bf16(v.x); o.y = f32_bf16(v.y); o.z = f32_bf16(v.z); o.w = f32_bf16(v.w);
  ((short4*)out)[i] = o;
}

// ---------------------------------------------------------------- rope tables
__global__ __launch_bounds__(256) void rope_tables_kernel(float* __restrict__ cosT,
                                                          float* __restrict__ sinT) {
  int idx = blockIdx.x * 256 + threadIdx.x;   // S*64
  if (idx >= SS * 64) return;
  int s = idx >> 6, t = idx & 63;
  float invf = exp2f(-(float)t * (18.931568569324174f / 64.0f));  // log2(500000)/64
  float fr = (float)s * invf;
  float sv, cv;
  sincosf(fr, &sv, &cv);
  cosT[idx] = cv;
  sinT[idx] = sv;
}

// ---------------------------------------------------------------- rope + scatter (Q,K only)
__global__ __launch_bounds__(256) void rope_scatter_kernel(const short* __restrict__ qkv,
    const float* __restrict__ cosT, const float* __restrict__ sinT,
    short* __restrict__ Qb, short* __restrict__ Kb) {
  int idx = blockIdx.x * 256 + threadIdx.x;   // B*S*40*64
  if (idx >= BB * SS * 40 * 64) return;
  int t = idx & 63;
  int hh = (idx >> 6) % 40;
  int bs = (idx >> 6) / 40;
  int s = bs & (SS - 1);
  int b = bs >> 11;
  const short* row = qkv + (long)bs * QKVN + hh * HD;
  float x1 = bf16_f32(row[t]);
  float x2 = bf16_f32(row[t + 64]);
  float c = cosT[(s << 6) + t], sn = sinT[(s << 6) + t];
  float o1 = x1 * c - x2 * sn;
  float o2 = x2 * c + x1 * sn;
  if (hh < 32) {
    const float sc = 0.08838834764831845f;  // 1/sqrt(128), folded into Q
    o1 *= sc; o2 *= sc;
    short* q = Qb + ((long)(b * NH + hh) * SS + s) * HD;
    q[t] = f32_bf16(o1); q[t + 64] = f32_bf16(o2);
  } else {
    short* k = Kb + ((long)(b * NKVH + (hh - 32)) * SS + s) * HD;
    k[t] = f32_bf16(o1); k[t + 64] = f32_bf16(o2);
  }
}

// ---------------------------------------------------------------- V transpose scatter
__global__ __launch_bounds__(256) void v_scatter_kernel(const short* __restrict__ qkv,
                                                        short* __restrict__ Vtb) {
  int bid = blockIdx.x;                 // 512 = B * NKVH * (SS/64)
  int s0 = (bid & 31) << 6;
  int kvh = (bid >> 5) & 7;
  int b = bid >> 8;
  const short* src = qkv + (long)(b * SS + s0) * QKVN + 5120 + kvh * HD;
  short* dst = Vtb + ((long)(b * NKVH + kvh) * HD) * SS + s0;
  int w = threadIdx.x >> 6, l = threadIdx.x & 63;
#pragma unroll
  for (int it = 0; it < 32; ++it) {
    int d = (it << 2) + w;
    dst[(long)d * SS + l] = src[(long)l * QKVN + d];
  }
}

// ---------------------------------------------------------------- GEMM: C[M,N] = A[M,K] @ B[N,K]^T
// XOR-swizzled LDS (T2): 16B slot ^= row&7; global_load_lds dest linear, source
// column pre-swizzled (rule #21). Conflicts 7.55e7 -> ~0 (round 2 verified).
template <int STORE_BF16>
__global__ __launch_bounds__(256) void gemm_bt_kernel(const short* __restrict__ A,
    const short* __restrict__ B, void* __restrict__ Cv, int M, int N, int K) {
  __shared__ __align__(16) short As[128 * 64];
  __shared__ __align__(16) short Bs[128 * 64];
  const int tid = threadIdx.x;
  const int wave = tid >> 6, lane = tid & 63;
  const int quad = lane >> 4, l16 = lane & 15;
  const int m0 = blockIdx.y << 7, n0 = blockIdx.x << 7;
  const int wm = (wave & 1) << 6, wn = (wave >> 1) << 6;
  const int sr = tid >> 3;                       // staged LDS row (0..31, +i*32)
  const int scs = (((tid & 7) ^ (sr & 7)) << 3); // pre-swizzled source column
  const int xr = l16 & 7;                        // read-side row XOR key

  f32x4 acc[4][4];
#pragma unroll
  for (int i = 0; i < 4; i++)
#pragma unroll
    for (int j = 0; j < 4; j++) acc[i][j] = (f32x4){0.f, 0.f, 0.f, 0.f};

  const short* Ag = A + (long)(m0 + sr) * K + scs;
  const short* Bg = B + (long)(n0 + sr) * K + scs;
  short* Asw = &As[sr * 64 + ((tid & 7) << 3)];  // linear dest = base + lane*16
  short* Bsw = &Bs[sr * 64 + ((tid & 7) << 3)];

  for (int k0 = 0; k0 < K; k0 += 64) {
#pragma unroll
    for (int i = 0; i < 4; i++) {
      async16(Ag + (long)(i * 32) * K + k0, Asw + i * 32 * 64);
      async16(Bg + (long)(i * 32) * K + k0, Bsw + i * 32 * 64);
    }
    __syncthreads();
#pragma unroll
    for (int kk = 0; kk < 64; kk += 32) {
      const int slot = ((quad + (kk >> 3)) ^ xr) << 3;   // swizzled 8-elem slot
      bf16x8 a[4], b[4];
#pragma unroll
      for (int i = 0; i < 4; i++)
        a[i] = *(const bf16x8*)&As[(wm + i * 16 + l16) * 64 + slot];
#pragma unroll
      for (int j = 0; j < 4; j++)
        b[j] = *(const bf16x8*)&Bs[(wn + j * 16 + l16) * 64 + slot];
#pragma unroll
      for (int i = 0; i < 4; i++)
#pragma unroll
        for (int j = 0; j < 4; j++)
          acc[i][j] = __builtin_amdgcn_mfma_f32_16x16x32_bf16(a[i], b[j], acc[i][j], 0, 0, 0);
    }
    __syncthreads();
  }
#pragma unroll
  for (int i = 0; i < 4; i++)
#pragma unroll
    for (int j = 0; j < 4; j++)
#pragma unroll
      for (int r = 0; r < 4; r++) {
        long row = m0 + wm + i * 16 + quad * 4 + r;
        long col = n0 + wn + j * 16 + l16;
        if (STORE_BF16)
          ((short*)Cv)[row * N + col] = f32_bf16(acc[i][j][r]);
        else
          ((float*)Cv)[row * N + col] = acc[i][j][r];
      }
}

// ---------------------------------------------------------------- flash attention v8.1
// v8 structure (16 rows/wave, 16 waves/CU, block-shared swizzled K staging) with
// two fixes for v8's replay-intermittent divergence:
//  - RACE FIX: explicit `s_waitcnt vmcnt(0)` + sched_barrier(0) BEFORE the
//    top-of-loop __syncthreads. global_load_lds has no register dest; if the
//    legalizer omits the vmcnt drain at that barrier, a wave can enter with
//    staging in flight -> another wave reads a torn K tile (RAW). The explicit
//    drain makes each wave retire its own staging before the barrier (m152-class
//    fix). WAR is structurally excluded by barrier-2.
//  - VGPR FIX: vfb batch moved AFTER PV0 -> peak V regs 32 not 64; peak live
//    ~100 < 128 cap of __launch_bounds__(256,4). WRITE_SIZE is the spill tripwire.
#define PSS 72   // P LDS row stride (elements): 144B, 16B-multiple, pad vs conflicts

#define LDK(dst, jcol)                                                              \
  {                                                                                 \
    const int rb_ = ((jcol) * 16 + l16) * 128;                                      \
    _Pragma("unroll") for (int kk_ = 0; kk_ < 4; kk_++)                             \
        dst[kk_] = *(const bf16x8*)&Ks[rb_ + (((((kk_ << 2) + quad) ^ xk)) << 3)];  \
  }

__global__ __launch_bounds__(256, 4) void flash_attn_kernel(const short* __restrict__ Q,
    const short* __restrict__ Kt, const short* __restrict__ Vt, short* __restrict__ O) {
  __shared__ __align__(16) short Ks[64 * 128];   // 16KB staged K tile (swizzled)
  __shared__ __align__(16) short Ps[4][16 * PSS];
  const int tid = threadIdx.x;
  const int wave = tid >> 6, lane = tid & 63;
  const int quad = lane >> 4, l16 = lane & 15;
  const int xk = l16 & 7;                        // K-LDS read-side XOR key

  // XCD co-location decode: 1024 blocks; blocks sharing (b,kvh) share bid%8.
  const int flat = blockIdx.x;
  const int xcd = flat & 7;
  const int idx = flat >> 3;          // 0..127
  const int gsel = idx >> 6;          // 0..1
  const int jj = idx & 63;            // 0..63
  const int g = xcd * 2 + gsel;       // 0..15 = (b,kvh) group
  const int b = g >> 3, kvh = g & 7;
  const int h = (kvh << 2) + (jj >> 4);
  const int gb = jj & 15;             // 0..15: 64-row macro-tile index

  const short* Kb = Kt + (long)(b * NKVH + kvh) * SS * HD;
  const short* Vb = Vt + (long)(b * NKVH + kvh) * HD * SS;
  short* Pw = &Ps[wave][0];

  // K staging geometry: thread stages 4x16B; LDS dest linear (base + lane*16),
  // source slot pre-swizzled so that LDS[row][slot] holds K[row][slot^(row&7)].
  const int srow = tid >> 4;          // 0..15 (+16 per it)
  const int lslot = tid & 15;
  const int sslot = lslot ^ (srow & 7);   // (it*16 preserves row&7)

  // Two causal-complementary 16-row Q-groups per wave: half0 tiles = gb+1,
  // half1 = 32-gb, identical across the block's 4 waves; total 33 per wave.
#pragma unroll 1
  for (int half = 0; half < 2; half++) {
    const int gq = half ? (127 - ((gb << 2) + wave)) : ((gb << 2) + wave);
    const int q0w = gq << 4;
    const int nfull = q0w >> 6;       // last tile index; uniform across waves

    const short* Qw = Q + ((long)(b * NH + h) * SS + q0w) * HD;
    bf16x8 qf[4];
#pragma unroll
    for (int kk = 0; kk < 4; kk++)
      qf[kk] = *(const bf16x8*)&Qw[l16 * HD + kk * 32 + quad * 8];

    f32x4 oacc[8];
#pragma unroll
    for (int jo = 0; jo < 8; jo++) oacc[jo] = (f32x4){0.f, 0.f, 0.f, 0.f};
    float l_i[4];
#pragma unroll
    for (int r = 0; r < 4; r++) l_i[r] = 0.f;

    // prologue: stage K tile 0 (Ks reads of prior half all retired: barrier-2)
#pragma unroll
    for (int it = 0; it < 4; it++) {
      const int r = srow + it * 16;
      async16(Kb + (long)r * HD + sslot * 8, &Ks[r * 128 + lslot * 8]);
    }

#pragma unroll 1
    for (int t = 0; t <= nfull; t++) {
      const int j0 = t << 6;
      const bool last = (t == nfull);
      // Explicit drain of this wave's staging BEFORE the barrier (race fix):
      asm volatile("s_waitcnt vmcnt(0)" ::: "memory");
      __builtin_amdgcn_sched_barrier(0);
      __syncthreads();                 // all waves' staging landed; aligns waves

      // QK from LDS (rolling 2 j-groups, 32 regs peak for K frags)
      f32x4 sc[4];
#pragma unroll
      for (int j = 0; j < 4; j++) sc[j] = (f32x4){0.f, 0.f, 0.f, 0.f};
      bf16x8 ka[4], kb_[4];
      LDK(ka, 0);
      LDK(kb_, 1);
      __builtin_amdgcn_s_setprio(1);
#pragma unroll
      for (int kk = 0; kk < 4; kk++)
        sc[0] = __builtin_amdgcn_mfma_f32_16x16x32_bf16(qf[kk], ka[kk], sc[0], 0, 0, 0);
      __builtin_amdgcn_s_setprio(0);
      LDK(ka, 2);
      __builtin_amdgcn_s_setprio(1);
#pragma unroll
      for (int kk = 0; kk < 4; kk++)
        sc[1] = __builtin_amdgcn_mfma_f32_16x16x32_bf16(qf[kk], kb_[kk], sc[1], 0, 0, 0);
      __builtin_amdgcn_s_setprio(0);
      LDK(kb_, 3);
      __builtin_amdgcn_s_setprio(1);
#pragma unroll
      for (int kk = 0; kk < 4; kk++)
        sc[2] = __builtin_amdgcn_mfma_f32_16x16x32_bf16(qf[kk], ka[kk], sc[2], 0, 0, 0);
#pragma unroll
      for (int kk = 0; kk < 4; kk++)
        sc[3] = __builtin_amdgcn_mfma_f32_16x16x32_bf16(qf[kk], kb_[kk], sc[3], 0, 0, 0);
      __builtin_amdgcn_s_setprio(0);
      __syncthreads();                 // all waves done reading Ks tile t

      // stage K tile t+1 (overlaps exp/P/PV; next-iter explicit drain + barrier)
      if (!last) {
        const short* src = Kb + (long)(j0 + 64) * HD;
#pragma unroll
        for (int it = 0; it < 4; it++) {
          const int r = srow + it * 16;
          async16(src + (long)r * HD + sslot * 8, &Ks[r * 128 + lslot * 8]);
        }
      }

      // V first half (kv=0): latency hides under mask/exp/P-write
      bf16x8 vfa[8];
#pragma unroll
      for (int jo = 0; jo < 8; jo++)
        vfa[jo] = *(const bf16x8*)&Vb[(long)(jo * 16 + l16) * SS + j0 + quad * 8];

      if (last) {
#pragma unroll
        for (int r = 0; r < 4; r++) {
          int row = q0w + quad * 4 + r;
#pragma unroll
          for (int j = 0; j < 4; j++) {
            int col = j0 + j * 16 + l16;
            if (col > row) sc[j][r] = -3.0e38f;
          }
        }
      }

      // p = exp(s); per-lane row-sum partials (max-free)
#pragma unroll
      for (int r = 0; r < 4; r++) {
        float ps = 0.f;
#pragma unroll
        for (int j = 0; j < 4; j++) {
          float p = __builtin_amdgcn_exp2f(sc[j][r] * LOG2E);
          sc[j][r] = p;
          ps += p;
        }
        l_i[r] += ps;
      }

      // P: C-layout -> per-wave LDS -> A-layout
#pragma unroll
      for (int j = 0; j < 4; j++)
#pragma unroll
        for (int r = 0; r < 4; r++)
          Pw[(quad * 4 + r) * PSS + j * 16 + l16] = f32_bf16(sc[j][r]);
      asm volatile("s_waitcnt lgkmcnt(0)" ::: "memory");
      bf16x8 ap0 = *(const bf16x8*)&Pw[l16 * PSS + quad * 8];
      bf16x8 ap1 = *(const bf16x8*)&Pw[l16 * PSS + 32 + quad * 8];

      __builtin_amdgcn_s_setprio(1);
#pragma unroll
      for (int jo = 0; jo < 8; jo++)
        oacc[jo] = __builtin_amdgcn_mfma_f32_16x16x32_bf16(ap0, vfa[jo], oacc[jo], 0, 0, 0);
      __builtin_amdgcn_s_setprio(0);

      // V second half (kv=1) AFTER PV0: peak V regs 32 not 64 (VGPR<=128 cap)
      bf16x8 vfb[8];
#pragma unroll
      for (int jo = 0; jo < 8; jo++)
        vfb[jo] = *(const bf16x8*)&Vb[(long)(jo * 16 + l16) * SS + j0 + 32 + quad * 8];

      __builtin_amdgcn_s_setprio(1);
#pragma unroll
      for (int jo = 0; jo < 8; jo++)
        oacc[jo] = __builtin_amdgcn_mfma_f32_16x16x32_bf16(ap1, vfb[jo], oacc[jo], 0, 0, 0);
      __builtin_amdgcn_s_setprio(0);
    }

    // epilogue: reduce l across the 16 lanes of each quad (once), store
    short* Ob = O + (long)(b * SS + q0w) * DD + h * HD;
#pragma unroll
    for (int r = 0; r < 4; r++) {
      float s = l_i[r];
      s += __shfl_xor(s, 1, 64);
      s += __shfl_xor(s, 2, 64);
      s += __shfl_xor(s, 4, 64);
      s += __shfl_xor(s, 8, 64);
      float inv = 1.0f / s;
      int row = quad * 4 + r;
#pragma unroll
      for (int jo = 0; jo < 8; jo++)
        Ob[(long)row * DD + jo * 16 + l16] = f32_bf16(oacc[jo][r] * inv);
    }
  }
}

// ---------------------------------------------------------------- launch
extern "C" void kernel_launch(void* const* d_in, const int* in_sizes, int n_in,
                              void* d_out, int out_size, void* d_ws, size_t ws_size,
                              hipStream_t stream) {
  (void)in_sizes; (void)n_in; (void)out_size; (void)ws_size;
  const float* x    = (const float*)d_in[0];
  const float* Wqkv = (const float*)d_in[1];
  const float* Wo   = (const float*)d_in[2];
  char* ws = (char*)d_ws;
  short* xb    = (short*)(ws + 0);            // x bf16 (33.5MB); reused as attn out
  short* wqkvb = (short*)(ws + 33554432);     // Wqkv bf16 (50.3MB)
  short* qkvb  = (short*)(ws + 83886080);     // qkv (50.3MB); reused as Wo bf16
  short* Qb    = (short*)(ws + 134217728);    // 33.5MB
  short* Kb    = (short*)(ws + 167772160);    // 8.4MB
  short* Vtb   = (short*)(ws + 176160768);    // 8.4MB
  float* cosT  = (float*)(ws + 184549376);    // 0.5MB
  float* sinT  = (float*)(ws + 185073664);    // 0.5MB
  short* wob   = qkvb;
  short* attnb = xb;

  cast_bf16_kernel<<<16384, 256, 0, stream>>>(x, xb, 4194304);
  cast_bf16_kernel<<<24576, 256, 0, stream>>>(Wqkv, wqkvb, 6291456);
  gemm_bt_kernel<1><<<dim3(QKVN / 128, MROWS / 128), 256, 0, stream>>>(
      xb, wqkvb, (void*)qkvb, MROWS, QKVN, DD);
  rope_tables_kernel<<<512, 256, 0, stream>>>(cosT, sinT);
  rope_scatter_kernel<<<40960, 256, 0, stream>>>(qkvb, cosT, sinT, Qb, Kb);
  v_scatter_kernel<<<512, 256, 0, stream>>>(qkvb, Vtb);
  cast_bf16_kernel<<<16384, 256, 0, stream>>>(Wo, wob, 4194304);   // overwrites qkvb (dead)
  flash_attn_kernel<<<1024, 256, 0, stream>>>(Qb, Kb, Vtb, attnb);
  gemm_bt_kernel<0><<<dim3(DD / 128, MROWS / 128), 256, 0, stream>>>(
      attnb, wob, d_out, MROWS, DD, DD);
}

// Round 7
// 896.132 us; speedup vs baseline: 1.1170x; 1.0239x over previous
//
#include <hip/hip_runtime.h>
#include <stdint.h>

// Problem constants
#define BB 2
#define SS 2048
#define DD 4096
#define NH 32
#define NKVH 8
#define HD 128
#define QKVN 6144          // (32 + 2*8) * 128
#define MROWS (BB * SS)    // 4096
#define LOG2E 1.4426950408889634f

typedef short bf16x8 __attribute__((ext_vector_type(8)));   // 8 bf16 in 4 VGPRs
typedef float f32x4 __attribute__((ext_vector_type(4)));

__device__ __forceinline__ short f32_bf16(float f) {
  union { float f; unsigned u; } c; c.f = f;
  unsigned r = (c.u + 0x7fffu + ((c.u >> 16) & 1u)) >> 16;   // RNE
  return (short)r;
}
__device__ __forceinline__ float bf16_f32(short h) {
  union { unsigned u; float f; } c; c.u = ((unsigned)(unsigned short)h) << 16;
  return c.f;
}

// async global->LDS, 16B per lane. LDS dest must be wave-uniform base + lane*16.
__device__ __forceinline__ void async16(const void* g, void* l) {
  __builtin_amdgcn_global_load_lds(
      (const __attribute__((address_space(1))) unsigned int*)(uintptr_t)g,
      (__attribute__((address_space(3))) unsigned int*)(uintptr_t)l,
      16, 0, 0);
}

// ---------------------------------------------------------------- cast f32 -> bf16
__global__ __launch_bounds__(256) void cast_bf16_kernel(const float* __restrict__ in,
                                                        short* __restrict__ out, int n4) {
  int i = blockIdx.x * 256 + threadIdx.x;
  if (i >= n4) return;
  float4 v = ((const float4*)in)[i];
  short4 o;
  o.x = f32_bf16(v.x); o.y = f32_bf16(v.y); o.z = f32_bf16(v.z); o.w = f32_bf16(v.w);
  ((short4*)out)[i] = o;
}

// ---------------------------------------------------------------- rope tables
__global__ __launch_bounds__(256) void rope_tables_kernel(float* __restrict__ cosT,
                                                          float* __restrict__ sinT) {
  int idx = blockIdx.x * 256 + threadIdx.x;   // S*64
  if (idx >= SS * 64) return;
  int s = idx >> 6, t = idx & 63;
  float invf = exp2f(-(float)t * (18.931568569324174f / 64.0f));  // log2(500000)/64
  float fr = (float)s * invf;
  float sv, cv;
  sincosf(fr, &sv, &cv);
  cosT[idx] = cv;
  sinT[idx] = sv;
}

// ---------------------------------------------------------------- rope + scatter (Q,K only)
__global__ __launch_bounds__(256) void rope_scatter_kernel(const short* __restrict__ qkv,
    const float* __restrict__ cosT, const float* __restrict__ sinT,
    short* __restrict__ Qb, short* __restrict__ Kb) {
  int idx = blockIdx.x * 256 + threadIdx.x;   // B*S*40*64
  if (idx >= BB * SS * 40 * 64) return;
  int t = idx & 63;
  int hh = (idx >> 6) % 40;
  int bs = (idx >> 6) / 40;
  int s = bs & (SS - 1);
  int b = bs >> 11;
  const short* row = qkv + (long)bs * QKVN + hh * HD;
  float x1 = bf16_f32(row[t]);
  float x2 = bf16_f32(row[t + 64]);
  float c = cosT[(s << 6) + t], sn = sinT[(s << 6) + t];
  float o1 = x1 * c - x2 * sn;
  float o2 = x2 * c + x1 * sn;
  if (hh < 32) {
    const float sc = 0.08838834764831845f;  // 1/sqrt(128), folded into Q
    o1 *= sc; o2 *= sc;
    short* q = Qb + ((long)(b * NH + hh) * SS + s) * HD;
    q[t] = f32_bf16(o1); q[t + 64] = f32_bf16(o2);
  } else {
    short* k = Kb + ((long)(b * NKVH + (hh - 32)) * SS + s) * HD;
    k[t] = f32_bf16(o1); k[t + 64] = f32_bf16(o2);
  }
}

// ---------------------------------------------------------------- V transpose scatter
__global__ __launch_bounds__(256) void v_scatter_kernel(const short* __restrict__ qkv,
                                                        short* __restrict__ Vtb) {
  int bid = blockIdx.x;                 // 512 = B * NKVH * (SS/64)
  int s0 = (bid & 31) << 6;
  int kvh = (bid >> 5) & 7;
  int b = bid >> 8;
  const short* src = qkv + (long)(b * SS + s0) * QKVN + 5120 + kvh * HD;
  short* dst = Vtb + ((long)(b * NKVH + kvh) * HD) * SS + s0;
  int w = threadIdx.x >> 6, l = threadIdx.x & 63;
#pragma unroll
  for (int it = 0; it < 32; ++it) {
    int d = (it << 2) + w;
    dst[(long)d * SS + l] = src[(long)l * QKVN + d];
  }
}

// ---------------------------------------------------------------- GEMM: C[M,N] = A[M,K] @ B[N,K]^T
// XOR-swizzled LDS (T2): 16B slot ^= row&7; global_load_lds dest linear, source
// column pre-swizzled (rule #21). Conflicts 7.55e7 -> ~0 (round 2 verified).
template <int STORE_BF16>
__global__ __launch_bounds__(256) void gemm_bt_kernel(const short* __restrict__ A,
    const short* __restrict__ B, void* __restrict__ Cv, int M, int N, int K) {
  __shared__ __align__(16) short As[128 * 64];
  __shared__ __align__(16) short Bs[128 * 64];
  const int tid = threadIdx.x;
  const int wave = tid >> 6, lane = tid & 63;
  const int quad = lane >> 4, l16 = lane & 15;
  const int m0 = blockIdx.y << 7, n0 = blockIdx.x << 7;
  const int wm = (wave & 1) << 6, wn = (wave >> 1) << 6;
  const int sr = tid >> 3;                       // staged LDS row (0..31, +i*32)
  const int scs = (((tid & 7) ^ (sr & 7)) << 3); // pre-swizzled source column
  const int xr = l16 & 7;                        // read-side row XOR key

  f32x4 acc[4][4];
#pragma unroll
  for (int i = 0; i < 4; i++)
#pragma unroll
    for (int j = 0; j < 4; j++) acc[i][j] = (f32x4){0.f, 0.f, 0.f, 0.f};

  const short* Ag = A + (long)(m0 + sr) * K + scs;
  const short* Bg = B + (long)(n0 + sr) * K + scs;
  short* Asw = &As[sr * 64 + ((tid & 7) << 3)];  // linear dest = base + lane*16
  short* Bsw = &Bs[sr * 64 + ((tid & 7) << 3)];

  for (int k0 = 0; k0 < K; k0 += 64) {
#pragma unroll
    for (int i = 0; i < 4; i++) {
      async16(Ag + (long)(i * 32) * K + k0, Asw + i * 32 * 64);
      async16(Bg + (long)(i * 32) * K + k0, Bsw + i * 32 * 64);
    }
    __syncthreads();
#pragma unroll
    for (int kk = 0; kk < 64; kk += 32) {
      const int slot = ((quad + (kk >> 3)) ^ xr) << 3;   // swizzled 8-elem slot
      bf16x8 a[4], b[4];
#pragma unroll
      for (int i = 0; i < 4; i++)
        a[i] = *(const bf16x8*)&As[(wm + i * 16 + l16) * 64 + slot];
#pragma unroll
      for (int j = 0; j < 4; j++)
        b[j] = *(const bf16x8*)&Bs[(wn + j * 16 + l16) * 64 + slot];
#pragma unroll
      for (int i = 0; i < 4; i++)
#pragma unroll
        for (int j = 0; j < 4; j++)
          acc[i][j] = __builtin_amdgcn_mfma_f32_16x16x32_bf16(a[i], b[j], acc[i][j], 0, 0, 0);
    }
    __syncthreads();
  }
#pragma unroll
  for (int i = 0; i < 4; i++)
#pragma unroll
    for (int j = 0; j < 4; j++)
#pragma unroll
      for (int r = 0; r < 4; r++) {
        long row = m0 + wm + i * 16 + quad * 4 + r;
        long col = n0 + wn + j * 16 + l16;
        if (STORE_BF16)
          ((short*)Cv)[row * N + col] = f32_bf16(acc[i][j][r]);
        else
          ((float*)Cv)[row * N + col] = acc[i][j][r];
      }
}

// ---------------------------------------------------------------- flash attention v8.2
// v8.1 was race-free but SPILLED: __launch_bounds__(256,4) caps VGPR at 256/N=64
// on this toolchain (empirical: N=2->128 [v7], N=3->84 [v3 note], N=4->64 [v8.1]),
// vs a ~100-110 live set -> 31MB scratch writes in the inner loop (WRITE_SIZE
// 64.4MB vs 33.5 baseline). v8.2 changes EXACTLY ONE thing: (256,2) -> cap 128.
// Hardware residency is unchanged: 4 blocks/CU needs VGPR<=2048/16=128 and
// LDS 4x25.6KB=102KB<=160KB, grid 1024 = 4 blocks/CU = 16 waves/CU.
// (Bank conflicts 9.7M = ~38K cy/CU vs 727K total = 5% tax; not the lever.)
#define PSS 72   // P LDS row stride (elements): 144B, 16B-multiple, pad vs conflicts

#define LDK(dst, jcol)                                                              \
  {                                                                                 \
    const int rb_ = ((jcol) * 16 + l16) * 128;                                      \
    _Pragma("unroll") for (int kk_ = 0; kk_ < 4; kk_++)                             \
        dst[kk_] = *(const bf16x8*)&Ks[rb_ + (((((kk_ << 2) + quad) ^ xk)) << 3)];  \
  }

__global__ __launch_bounds__(256, 2) void flash_attn_kernel(const short* __restrict__ Q,
    const short* __restrict__ Kt, const short* __restrict__ Vt, short* __restrict__ O) {
  __shared__ __align__(16) short Ks[64 * 128];   // 16KB staged K tile (swizzled)
  __shared__ __align__(16) short Ps[4][16 * PSS];
  const int tid = threadIdx.x;
  const int wave = tid >> 6, lane = tid & 63;
  const int quad = lane >> 4, l16 = lane & 15;
  const int xk = l16 & 7;                        // K-LDS read-side XOR key

  // XCD co-location decode: 1024 blocks; blocks sharing (b,kvh) share bid%8.
  const int flat = blockIdx.x;
  const int xcd = flat & 7;
  const int idx = flat >> 3;          // 0..127
  const int gsel = idx >> 6;          // 0..1
  const int jj = idx & 63;            // 0..63
  const int g = xcd * 2 + gsel;       // 0..15 = (b,kvh) group
  const int b = g >> 3, kvh = g & 7;
  const int h = (kvh << 2) + (jj >> 4);
  const int gb = jj & 15;             // 0..15: 64-row macro-tile index

  const short* Kb = Kt + (long)(b * NKVH + kvh) * SS * HD;
  const short* Vb = Vt + (long)(b * NKVH + kvh) * HD * SS;
  short* Pw = &Ps[wave][0];

  // K staging geometry: thread stages 4x16B; LDS dest linear (base + lane*16),
  // source slot pre-swizzled so that LDS[row][slot] holds K[row][slot^(row&7)].
  const int srow = tid >> 4;          // 0..15 (+16 per it)
  const int lslot = tid & 15;
  const int sslot = lslot ^ (srow & 7);   // (it*16 preserves row&7)

  // Two causal-complementary 16-row Q-groups per wave: half0 tiles = gb+1,
  // half1 = 32-gb, identical across the block's 4 waves; total 33 per wave.
#pragma unroll 1
  for (int half = 0; half < 2; half++) {
    const int gq = half ? (127 - ((gb << 2) + wave)) : ((gb << 2) + wave);
    const int q0w = gq << 4;
    const int nfull = q0w >> 6;       // last tile index; uniform across waves

    const short* Qw = Q + ((long)(b * NH + h) * SS + q0w) * HD;
    bf16x8 qf[4];
#pragma unroll
    for (int kk = 0; kk < 4; kk++)
      qf[kk] = *(const bf16x8*)&Qw[l16 * HD + kk * 32 + quad * 8];

    f32x4 oacc[8];
#pragma unroll
    for (int jo = 0; jo < 8; jo++) oacc[jo] = (f32x4){0.f, 0.f, 0.f, 0.f};
    float l_i[4];
#pragma unroll
    for (int r = 0; r < 4; r++) l_i[r] = 0.f;

    // prologue: stage K tile 0 (Ks reads of prior half all retired: barrier-2)
#pragma unroll
    for (int it = 0; it < 4; it++) {
      const int r = srow + it * 16;
      async16(Kb + (long)r * HD + sslot * 8, &Ks[r * 128 + lslot * 8]);
    }

#pragma unroll 1
    for (int t = 0; t <= nfull; t++) {
      const int j0 = t << 6;
      const bool last = (t == nfull);
      // Explicit drain of this wave's staging BEFORE the barrier (race fix):
      asm volatile("s_waitcnt vmcnt(0)" ::: "memory");
      __builtin_amdgcn_sched_barrier(0);
      __syncthreads();                 // all waves' staging landed; aligns waves

      // QK from LDS (rolling 2 j-groups, 32 regs peak for K frags)
      f32x4 sc[4];
#pragma unroll
      for (int j = 0; j < 4; j++) sc[j] = (f32x4){0.f, 0.f, 0.f, 0.f};
      bf16x8 ka[4], kb_[4];
      LDK(ka, 0);
      LDK(kb_, 1);
      __builtin_amdgcn_s_setprio(1);
#pragma unroll
      for (int kk = 0; kk < 4; kk++)
        sc[0] = __builtin_amdgcn_mfma_f32_16x16x32_bf16(qf[kk], ka[kk], sc[0], 0, 0, 0);
      __builtin_amdgcn_s_setprio(0);
      LDK(ka, 2);
      __builtin_amdgcn_s_setprio(1);
#pragma unroll
      for (int kk = 0; kk < 4; kk++)
        sc[1] = __builtin_amdgcn_mfma_f32_16x16x32_bf16(qf[kk], kb_[kk], sc[1], 0, 0, 0);
      __builtin_amdgcn_s_setprio(0);
      LDK(kb_, 3);
      __builtin_amdgcn_s_setprio(1);
#pragma unroll
      for (int kk = 0; kk < 4; kk++)
        sc[2] = __builtin_amdgcn_mfma_f32_16x16x32_bf16(qf[kk], ka[kk], sc[2], 0, 0, 0);
#pragma unroll
      for (int kk = 0; kk < 4; kk++)
        sc[3] = __builtin_amdgcn_mfma_f32_16x16x32_bf16(qf[kk], kb_[kk], sc[3], 0, 0, 0);
      __builtin_amdgcn_s_setprio(0);
      __syncthreads();                 // all waves done reading Ks tile t

      // stage K tile t+1 (overlaps exp/P/PV; next-iter explicit drain + barrier)
      if (!last) {
        const short* src = Kb + (long)(j0 + 64) * HD;
#pragma unroll
        for (int it = 0; it < 4; it++) {
          const int r = srow + it * 16;
          async16(src + (long)r * HD + sslot * 8, &Ks[r * 128 + lslot * 8]);
        }
      }

      // V first half (kv=0): latency hides under mask/exp/P-write
      bf16x8 vfa[8];
#pragma unroll
      for (int jo = 0; jo < 8; jo++)
        vfa[jo] = *(const bf16x8*)&Vb[(long)(jo * 16 + l16) * SS + j0 + quad * 8];

      if (last) {
#pragma unroll
        for (int r = 0; r < 4; r++) {
          int row = q0w + quad * 4 + r;
#pragma unroll
          for (int j = 0; j < 4; j++) {
            int col = j0 + j * 16 + l16;
            if (col > row) sc[j][r] = -3.0e38f;
          }
        }
      }

      // p = exp(s); per-lane row-sum partials (max-free)
#pragma unroll
      for (int r = 0; r < 4; r++) {
        float ps = 0.f;
#pragma unroll
        for (int j = 0; j < 4; j++) {
          float p = __builtin_amdgcn_exp2f(sc[j][r] * LOG2E);
          sc[j][r] = p;
          ps += p;
        }
        l_i[r] += ps;
      }

      // P: C-layout -> per-wave LDS -> A-layout
#pragma unroll
      for (int j = 0; j < 4; j++)
#pragma unroll
        for (int r = 0; r < 4; r++)
          Pw[(quad * 4 + r) * PSS + j * 16 + l16] = f32_bf16(sc[j][r]);
      asm volatile("s_waitcnt lgkmcnt(0)" ::: "memory");
      bf16x8 ap0 = *(const bf16x8*)&Pw[l16 * PSS + quad * 8];
      bf16x8 ap1 = *(const bf16x8*)&Pw[l16 * PSS + 32 + quad * 8];

      __builtin_amdgcn_s_setprio(1);
#pragma unroll
      for (int jo = 0; jo < 8; jo++)
        oacc[jo] = __builtin_amdgcn_mfma_f32_16x16x32_bf16(ap0, vfa[jo], oacc[jo], 0, 0, 0);
      __builtin_amdgcn_s_setprio(0);

      // V second half (kv=1) AFTER PV0: peak V regs 32 not 64
      bf16x8 vfb[8];
#pragma unroll
      for (int jo = 0; jo < 8; jo++)
        vfb[jo] = *(const bf16x8*)&Vb[(long)(jo * 16 + l16) * SS + j0 + 32 + quad * 8];

      __builtin_amdgcn_s_setprio(1);
#pragma unroll
      for (int jo = 0; jo < 8; jo++)
        oacc[jo] = __builtin_amdgcn_mfma_f32_16x16x32_bf16(ap1, vfb[jo], oacc[jo], 0, 0, 0);
      __builtin_amdgcn_s_setprio(0);
    }

    // epilogue: reduce l across the 16 lanes of each quad (once), store
    short* Ob = O + (long)(b * SS + q0w) * DD + h * HD;
#pragma unroll
    for (int r = 0; r < 4; r++) {
      float s = l_i[r];
      s += __shfl_xor(s, 1, 64);
      s += __shfl_xor(s, 2, 64);
      s += __shfl_xor(s, 4, 64);
      s += __shfl_xor(s, 8, 64);
      float inv = 1.0f / s;
      int row = quad * 4 + r;
#pragma unroll
      for (int jo = 0; jo < 8; jo++)
        Ob[(long)row * DD + jo * 16 + l16] = f32_bf16(oacc[jo][r] * inv);
    }
  }
}

// ---------------------------------------------------------------- launch
extern "C" void kernel_launch(void* const* d_in, const int* in_sizes, int n_in,
                              void* d_out, int out_size, void* d_ws, size_t ws_size,
                              hipStream_t stream) {
  (void)in_sizes; (void)n_in; (void)out_size; (void)ws_size;
  const float* x    = (const float*)d_in[0];
  const float* Wqkv = (const float*)d_in[1];
  const float* Wo   = (const float*)d_in[2];
  char* ws = (char*)d_ws;
  short* xb    = (short*)(ws + 0);            // x bf16 (33.5MB); reused as attn out
  short* wqkvb = (short*)(ws + 33554432);     // Wqkv bf16 (50.3MB)
  short* qkvb  = (short*)(ws + 83886080);     // qkv (50.3MB); reused as Wo bf16
  short* Qb    = (short*)(ws + 134217728);    // 33.5MB
  short* Kb    = (short*)(ws + 167772160);    // 8.4MB
  short* Vtb   = (short*)(ws + 176160768);    // 8.4MB
  float* cosT  = (float*)(ws + 184549376);    // 0.5MB
  float* sinT  = (float*)(ws + 185073664);    // 0.5MB
  short* wob   = qkvb;
  short* attnb = xb;

  cast_bf16_kernel<<<16384, 256, 0, stream>>>(x, xb, 4194304);
  cast_bf16_kernel<<<24576, 256, 0, stream>>>(Wqkv, wqkvb, 6291456);
  gemm_bt_kernel<1><<<dim3(QKVN / 128, MROWS / 128), 256, 0, stream>>>(
      xb, wqkvb, (void*)qkvb, MROWS, QKVN, DD);
  rope_tables_kernel<<<512, 256, 0, stream>>>(cosT, sinT);
  rope_scatter_kernel<<<40960, 256, 0, stream>>>(qkvb, cosT, sinT, Qb, Kb);
  v_scatter_kernel<<<512, 256, 0, stream>>>(qkvb, Vtb);
  cast_bf16_kernel<<<16384, 256, 0, stream>>>(Wo, wob, 4194304);   // overwrites qkvb (dead)
  flash_attn_kernel<<<1024, 256, 0, stream>>>(Qb, Kb, Vtb, attnb);
  gemm_bt_kernel<0><<<dim3(DD / 128, MROWS / 128), 256, 0, stream>>>(
      attnb, wob, d_out, MROWS, DD, DD);
}

// Round 8
// 869.479 us; speedup vs baseline: 1.1513x; 1.0307x over previous
//
#include <hip/hip_runtime.h>
#include <stdint.h>

// Problem constants
#define BB 2
#define SS 2048
#define DD 4096
#define NH 32
#define NKVH 8
#define HD 128
#define QKVN 6144          // (32 + 2*8) * 128
#define MROWS (BB * SS)    // 4096
#define LOG2E 1.4426950408889634f

typedef short bf16x8 __attribute__((ext_vector_type(8)));   // 8 bf16 in 4 VGPRs
typedef float f32x4 __attribute__((ext_vector_type(4)));

__device__ __forceinline__ short f32_bf16(float f) {
  union { float f; unsigned u; } c; c.f = f;
  unsigned r = (c.u + 0x7fffu + ((c.u >> 16) & 1u)) >> 16;   // RNE
  return (short)r;
}
__device__ __forceinline__ float bf16_f32(short h) {
  union { unsigned u; float f; } c; c.u = ((unsigned)(unsigned short)h) << 16;
  return c.f;
}

// async global->LDS, 16B per lane. LDS dest must be wave-uniform base + lane*16.
__device__ __forceinline__ void async16(const void* g, void* l) {
  __builtin_amdgcn_global_load_lds(
      (const __attribute__((address_space(1))) unsigned int*)(uintptr_t)g,
      (__attribute__((address_space(3))) unsigned int*)(uintptr_t)l,
      16, 0, 0);
}

// ---------------------------------------------------------------- cast f32 -> bf16
__global__ __launch_bounds__(256) void cast_bf16_kernel(const float* __restrict__ in,
                                                        short* __restrict__ out, int n4) {
  int i = blockIdx.x * 256 + threadIdx.x;
  if (i >= n4) return;
  float4 v = ((const float4*)in)[i];
  short4 o;
  o.x = f32_bf16(v.x); o.y = f32_bf16(v.y); o.z = f32_bf16(v.z); o.w = f32_bf16(v.w);
  ((short4*)out)[i] = o;
}

// ---------------------------------------------------------------- rope tables
__global__ __launch_bounds__(256) void rope_tables_kernel(float* __restrict__ cosT,
                                                          float* __restrict__ sinT) {
  int idx = blockIdx.x * 256 + threadIdx.x;   // S*64
  if (idx >= SS * 64) return;
  int s = idx >> 6, t = idx & 63;
  float invf = exp2f(-(float)t * (18.931568569324174f / 64.0f));  // log2(500000)/64
  float fr = (float)s * invf;
  float sv, cv;
  sincosf(fr, &sv, &cv);
  cosT[idx] = cv;
  sinT[idx] = sv;
}

// ---------------------------------------------------------------- rope + scatter (Q,K only)
__global__ __launch_bounds__(256) void rope_scatter_kernel(const short* __restrict__ qkv,
    const float* __restrict__ cosT, const float* __restrict__ sinT,
    short* __restrict__ Qb, short* __restrict__ Kb) {
  int idx = blockIdx.x * 256 + threadIdx.x;   // B*S*40*64
  if (idx >= BB * SS * 40 * 64) return;
  int t = idx & 63;
  int hh = (idx >> 6) % 40;
  int bs = (idx >> 6) / 40;
  int s = bs & (SS - 1);
  int b = bs >> 11;
  const short* row = qkv + (long)bs * QKVN + hh * HD;
  float x1 = bf16_f32(row[t]);
  float x2 = bf16_f32(row[t + 64]);
  float c = cosT[(s << 6) + t], sn = sinT[(s << 6) + t];
  float o1 = x1 * c - x2 * sn;
  float o2 = x2 * c + x1 * sn;
  if (hh < 32) {
    const float sc = 0.08838834764831845f;  // 1/sqrt(128), folded into Q
    o1 *= sc; o2 *= sc;
    short* q = Qb + ((long)(b * NH + hh) * SS + s) * HD;
    q[t] = f32_bf16(o1); q[t + 64] = f32_bf16(o2);
  } else {
    short* k = Kb + ((long)(b * NKVH + (hh - 32)) * SS + s) * HD;
    k[t] = f32_bf16(o1); k[t + 64] = f32_bf16(o2);
  }
}

// ---------------------------------------------------------------- V transpose scatter
__global__ __launch_bounds__(256) void v_scatter_kernel(const short* __restrict__ qkv,
                                                        short* __restrict__ Vtb) {
  int bid = blockIdx.x;                 // 512 = B * NKVH * (SS/64)
  int s0 = (bid & 31) << 6;
  int kvh = (bid >> 5) & 7;
  int b = bid >> 8;
  const short* src = qkv + (long)(b * SS + s0) * QKVN + 5120 + kvh * HD;
  short* dst = Vtb + ((long)(b * NKVH + kvh) * HD) * SS + s0;
  int w = threadIdx.x >> 6, l = threadIdx.x & 63;
#pragma unroll
  for (int it = 0; it < 32; ++it) {
    int d = (it << 2) + w;
    dst[(long)d * SS + l] = src[(long)l * QKVN + d];
  }
}

// ---------------------------------------------------------------- GEMM 256x256 8-phase (T2+T3+T4+T5)
// m201-template port: BM=BN=256, BK=64, 512 thr = 8 waves (2Mx4N), per-wave
// output 128x64 (acc[8][4]), LDS 128KB double-buffered. Per K-tile: 4 phases of
// {ds_read subtile -> s_barrier -> lgkmcnt(0)+sched_barrier -> setprio(1) ->
// 16 MFMA -> setprio(0) -> s_barrier}. Tile t+1 staged (8 global_load_lds/thread)
// at the TOP of tile t: a full tile of compute (~2.5K cy) hides the latency;
// explicit per-wave vmcnt(0)+sched_barrier before the tile-end barrier (v8 race
// lesson). Slot-XOR swizzle slot^=row&7 (proven round 2: 2-way = free), applied
// both-sides (rule #21: linear LDS dest, pre-swizzled global source, swizzled
// ds_read). Bijective XCD swizzle on a 1-D grid (nwg%8==0: 384, 256).
#define STAGE256(kt, bsel)                                                          \
  {                                                                                 \
    const long kbase_ = (long)(kt) << 6;                                            \
    _Pragma("unroll") for (int i_ = 0; i_ < 4; i_++) {                              \
      const int idx_ = tid + i_ * 512;                                              \
      const int row_ = idx_ >> 3, slot_ = idx_ & 7;                                 \
      const int ss_ = slot_ ^ (row_ & 7);                                           \
      async16(Ag0 + (long)row_ * K + kbase_ + ss_ * 8,                              \
              &Abuf[bsel][row_ * 64 + slot_ * 8]);                                  \
      async16(Bg0 + (long)row_ * K + kbase_ + ss_ * 8,                              \
              &Bbuf[bsel][row_ * 64 + slot_ * 8]);                                  \
    }                                                                               \
  }

#define GPHASE(p, LASTP)                                                            \
  {                                                                                 \
    bf16x8 afr[2][2];                                                               \
    _Pragma("unroll") for (int mi = 0; mi < 2; mi++)                                \
      _Pragma("unroll") for (int kk = 0; kk < 2; kk++)                              \
        afr[mi][kk] = *(const bf16x8*)&Ac[(((p) * 2 + mi) * 16 + l16) * 64 +        \
                                          ((((kk << 2) + quad) ^ xr) << 3)];        \
    __builtin_amdgcn_s_barrier();                                                   \
    asm volatile("s_waitcnt lgkmcnt(0)" ::: "memory");                              \
    __builtin_amdgcn_sched_barrier(0);                                              \
    __builtin_amdgcn_s_setprio(1);                                                  \
    _Pragma("unroll") for (int mi = 0; mi < 2; mi++)                                \
      _Pragma("unroll") for (int nr = 0; nr < 4; nr++)                              \
        _Pragma("unroll") for (int kk = 0; kk < 2; kk++)                            \
          acc[(p) * 2 + mi][nr] = __builtin_amdgcn_mfma_f32_16x16x32_bf16(          \
              afr[mi][kk], bfr[nr][kk], acc[(p) * 2 + mi][nr], 0, 0, 0);            \
    __builtin_amdgcn_s_setprio(0);                                                  \
    if (!(LASTP)) __builtin_amdgcn_s_barrier();                                     \
  }

template <int STORE_BF16>
__global__ __launch_bounds__(512) void gemm256_kernel(const short* __restrict__ A,
    const short* __restrict__ B, void* __restrict__ Cv, int M, int N, int K, int gx) {
  __shared__ __align__(16) short Abuf[2][256 * 64];   // 64KB
  __shared__ __align__(16) short Bbuf[2][256 * 64];   // 64KB
  const int tid = threadIdx.x;
  const int lane = tid & 63, wave = tid >> 6;
  const int quad = lane >> 4, l16 = lane & 15;
  const int wm = wave >> 2;          // 0..1: M-half
  const int wn = wave & 3;           // 0..3: N-quarter
  const int xr = l16 & 7;            // read-side XOR key (row&7; bases are %8==0)

  // bijective XCD swizzle: nwg % 8 == 0 for both call sites (384, 256)
  const int nwg = gridDim.x;
  const int cpx = nwg >> 3;
  const int wg = ((int)blockIdx.x & 7) * cpx + ((int)blockIdx.x >> 3);
  const int m0 = (wg / gx) << 8;
  const int n0 = (wg % gx) << 8;

  const short* Ag0 = A + (long)m0 * K;
  const short* Bg0 = B + (long)n0 * K;

  f32x4 acc[8][4];
#pragma unroll
  for (int mr = 0; mr < 8; mr++)
#pragma unroll
    for (int nr = 0; nr < 4; nr++) acc[mr][nr] = (f32x4){0.f, 0.f, 0.f, 0.f};

  const int nk = K >> 6;

  // prologue: stage tile 0 into buf0, drain, align
  STAGE256(0, 0);
  asm volatile("s_waitcnt vmcnt(0)" ::: "memory");
  __builtin_amdgcn_sched_barrier(0);
  __builtin_amdgcn_s_barrier();

  int cur = 0;
#pragma unroll 1
  for (int kt = 0; kt < nk; ++kt) {
    // issue next tile's staging first: full tile of compute hides the latency
    if (kt + 1 < nk) {
      if (cur == 0) { STAGE256(kt + 1, 1); } else { STAGE256(kt + 1, 0); }
    }
    const short* Ac = &Abuf[cur][wm * 128 * 64];
    const short* Bc = &Bbuf[cur][wn * 64 * 64];

    // B fragments for the whole tile (8 x ds_read_b128)
    bf16x8 bfr[4][2];
#pragma unroll
    for (int nr = 0; nr < 4; nr++)
#pragma unroll
      for (int kk = 0; kk < 2; kk++)
        bfr[nr][kk] = *(const bf16x8*)&Bc[(nr * 16 + l16) * 64 +
                                          ((((kk << 2) + quad) ^ xr) << 3)];
    GPHASE(0, 0)
    GPHASE(1, 0)
    GPHASE(2, 0)
    GPHASE(3, 1)

    // tile end: each wave drains its own staging, then all waves align
    asm volatile("s_waitcnt vmcnt(0)" ::: "memory");
    __builtin_amdgcn_sched_barrier(0);
    __builtin_amdgcn_s_barrier();
    cur ^= 1;
  }

  // epilogue
#pragma unroll
  for (int mr = 0; mr < 8; mr++)
#pragma unroll
    for (int nr = 0; nr < 4; nr++)
#pragma unroll
      for (int r = 0; r < 4; r++) {
        long row = m0 + wm * 128 + mr * 16 + quad * 4 + r;
        long col = n0 + wn * 64 + nr * 16 + l16;
        if (STORE_BF16)
          ((short*)Cv)[row * N + col] = f32_bf16(acc[mr][nr][r]);
        else
          ((float*)Cv)[row * N + col] = acc[mr][nr][r];
      }
}

// ---------------------------------------------------------------- flash attention v7 (round-4 proven: 261us)
// 32 Q-rows/wave, K batched to kf[16] before QK, V split vfa/vfb, XCD co-location,
// balanced causal pairing (33 tiles/wave). Frozen: v8 experiments (16 waves/CU)
// showed concurrency does NOT scale this kernel (282us at 2x waves) — limiter is
// occupancy-invariant; revisit with m214 structure if rounds permit.
#define PSS 72   // P LDS row stride (elements): 144B, 16B-multiple, pad vs conflicts

__global__ __launch_bounds__(256, 2) void flash_attn_kernel(const short* __restrict__ Q,
    const short* __restrict__ Kt, const short* __restrict__ Vt, short* __restrict__ O) {
  __shared__ __align__(16) short Ps[4][32 * PSS];
  const int tid = threadIdx.x;
  const int wave = tid >> 6, lane = tid & 63;
  const int quad = lane >> 4, l16 = lane & 15;

  // XCD co-location decode: 512 blocks; blocks sharing (b,kvh) share bid%8.
  const int flat = blockIdx.x;
  const int xcd = flat & 7;
  const int kk_ = flat >> 3;          // 0..63
  const int gsel = kk_ >> 5;          // 0..1
  const int jj = kk_ & 31;            // 0..31
  const int g = xcd * 2 + gsel;       // 0..15 = (b,kvh) group
  const int b = g >> 3, kvh = g & 7;
  const int h = (kvh << 2) + (jj >> 3);
  const int qb0 = jj & 7;

  const short* Kb = Kt + (long)(b * NKVH + kvh) * SS * HD;
  const short* Vb = Vt + (long)(b * NKVH + kvh) * HD * SS;
  short* Pw = &Ps[wave][0];

  // Two causal-complementary Q-groups per wave: exactly 33 key-tiles per wave.
#pragma unroll 1
  for (int half = 0; half < 2; half++) {
    const int qb = half ? (15 - qb0) : qb0;
    const int w = half ? (3 - wave) : wave;
    const int q0w = (qb << 7) + (w << 5);

    const short* Qw = Q + ((long)(b * NH + h) * SS + q0w) * HD;
    bf16x8 qf[2][4];
#pragma unroll
    for (int i = 0; i < 2; i++)
#pragma unroll
      for (int kk = 0; kk < 4; kk++)
        qf[i][kk] = *(const bf16x8*)&Qw[(i * 16 + l16) * HD + kk * 32 + quad * 8];

    f32x4 oacc[2][8];
#pragma unroll
    for (int i = 0; i < 2; i++)
#pragma unroll
      for (int jo = 0; jo < 8; jo++) oacc[i][jo] = (f32x4){0.f, 0.f, 0.f, 0.f};
    float l_i[2][4];
#pragma unroll
    for (int i = 0; i < 2; i++)
#pragma unroll
      for (int r = 0; r < 4; r++) l_i[i][r] = 0.f;

    const int nfull = q0w >> 6;            // last tile index (inclusive)

#pragma unroll 1
    for (int t = 0; t <= nfull; t++) {
      const int j0 = t << 6;
      const bool last = (t == nfull);

      // K tile: all 16 fragments issued back-to-back (one latency exposure)
      bf16x8 kf[16];
#pragma unroll
      for (int kk = 0; kk < 4; kk++)
#pragma unroll
        for (int j = 0; j < 4; j++)
          kf[kk * 4 + j] =
              *(const bf16x8*)&Kb[(long)(j0 + j * 16 + l16) * HD + kk * 32 + quad * 8];

      // scores S = Q K^T
      f32x4 sc[2][4];
#pragma unroll
      for (int i = 0; i < 2; i++)
#pragma unroll
        for (int j = 0; j < 4; j++) sc[i][j] = (f32x4){0.f, 0.f, 0.f, 0.f};
      __builtin_amdgcn_s_setprio(1);
#pragma unroll
      for (int kk = 0; kk < 4; kk++)
#pragma unroll
        for (int i = 0; i < 2; i++)
#pragma unroll
          for (int j = 0; j < 4; j++)
            sc[i][j] = __builtin_amdgcn_mfma_f32_16x16x32_bf16(qf[i][kk], kf[kk * 4 + j],
                                                               sc[i][j], 0, 0, 0);
      __builtin_amdgcn_s_setprio(0);

      // V first half (kv=0): latency hides under mask/exp/P-write
      bf16x8 vfa[8];
#pragma unroll
      for (int jo = 0; jo < 8; jo++)
        vfa[jo] = *(const bf16x8*)&Vb[(long)(jo * 16 + l16) * SS + j0 + quad * 8];

      if (last) {
#pragma unroll
        for (int i = 0; i < 2; i++)
#pragma unroll
          for (int r = 0; r < 4; r++) {
            int row = q0w + i * 16 + quad * 4 + r;
#pragma unroll
            for (int j = 0; j < 4; j++) {
              int col = j0 + j * 16 + l16;
              if (col > row) sc[i][j][r] = -3.0e38f;
            }
          }
      }

      // p = exp(s); per-lane row-sum partials (max-free)
#pragma unroll
      for (int i = 0; i < 2; i++)
#pragma unroll
        for (int r = 0; r < 4; r++) {
          float ps = 0.f;
#pragma unroll
          for (int j = 0; j < 4; j++) {
            float p = __builtin_amdgcn_exp2f(sc[i][j][r] * LOG2E);
            sc[i][j][r] = p;
            ps += p;
          }
          l_i[i][r] += ps;
        }

      // P: C-layout -> per-wave LDS -> A-layout
#pragma unroll
      for (int i = 0; i < 2; i++)
#pragma unroll
        for (int j = 0; j < 4; j++)
#pragma unroll
          for (int r = 0; r < 4; r++)
            Pw[(i * 16 + quad * 4 + r) * PSS + j * 16 + l16] = f32_bf16(sc[i][j][r]);
      asm volatile("s_waitcnt lgkmcnt(0)" ::: "memory");

      bf16x8 ap[2][2];
#pragma unroll
      for (int kv = 0; kv < 2; kv++) {
        ap[kv][0] = *(const bf16x8*)&Pw[l16 * PSS + kv * 32 + quad * 8];
        ap[kv][1] = *(const bf16x8*)&Pw[(16 + l16) * PSS + kv * 32 + quad * 8];
      }

      // V second half (kv=1): latency hides under PV0's 16 MFMAs
      bf16x8 vfb[8];
#pragma unroll
      for (int jo = 0; jo < 8; jo++)
        vfb[jo] = *(const bf16x8*)&Vb[(long)(jo * 16 + l16) * SS + j0 + 32 + quad * 8];

      __builtin_amdgcn_s_setprio(1);
#pragma unroll
      for (int jo = 0; jo < 8; jo++) {
        oacc[0][jo] = __builtin_amdgcn_mfma_f32_16x16x32_bf16(ap[0][0], vfa[jo],
                                                              oacc[0][jo], 0, 0, 0);
        oacc[1][jo] = __builtin_amdgcn_mfma_f32_16x16x32_bf16(ap[0][1], vfa[jo],
                                                              oacc[1][jo], 0, 0, 0);
      }
#pragma unroll
      for (int jo = 0; jo < 8; jo++) {
        oacc[0][jo] = __builtin_amdgcn_mfma_f32_16x16x32_bf16(ap[1][0], vfb[jo],
                                                              oacc[0][jo], 0, 0, 0);
        oacc[1][jo] = __builtin_amdgcn_mfma_f32_16x16x32_bf16(ap[1][1], vfb[jo],
                                                              oacc[1][jo], 0, 0, 0);
      }
      __builtin_amdgcn_s_setprio(0);
    }

    // epilogue: reduce l across the 16 lanes of each quad (once), store
    short* Ob = O + (long)(b * SS + q0w) * DD + h * HD;
#pragma unroll
    for (int i = 0; i < 2; i++)
#pragma unroll
      for (int r = 0; r < 4; r++) {
        float s = l_i[i][r];
        s += __shfl_xor(s, 1, 64);
        s += __shfl_xor(s, 2, 64);
        s += __shfl_xor(s, 4, 64);
        s += __shfl_xor(s, 8, 64);
        float inv = 1.0f / s;
        int row = i * 16 + quad * 4 + r;
#pragma unroll
        for (int jo = 0; jo < 8; jo++)
          Ob[(long)row * DD + jo * 16 + l16] = f32_bf16(oacc[i][jo][r] * inv);
      }
  }
}

// ---------------------------------------------------------------- launch
extern "C" void kernel_launch(void* const* d_in, const int* in_sizes, int n_in,
                              void* d_out, int out_size, void* d_ws, size_t ws_size,
                              hipStream_t stream) {
  (void)in_sizes; (void)n_in; (void)out_size; (void)ws_size;
  const float* x    = (const float*)d_in[0];
  const float* Wqkv = (const float*)d_in[1];
  const float* Wo   = (const float*)d_in[2];
  char* ws = (char*)d_ws;
  short* xb    = (short*)(ws + 0);            // x bf16 (33.5MB); reused as attn out
  short* wqkvb = (short*)(ws + 33554432);     // Wqkv bf16 (50.3MB)
  short* qkvb  = (short*)(ws + 83886080);     // qkv (50.3MB); reused as Wo bf16
  short* Qb    = (short*)(ws + 134217728);    // 33.5MB
  short* Kb    = (short*)(ws + 167772160);    // 8.4MB
  short* Vtb   = (short*)(ws + 176160768);    // 8.4MB
  float* cosT  = (float*)(ws + 184549376);    // 0.5MB
  float* sinT  = (float*)(ws + 185073664);    // 0.5MB
  short* wob   = qkvb;
  short* attnb = xb;

  cast_bf16_kernel<<<16384, 256, 0, stream>>>(x, xb, 4194304);
  cast_bf16_kernel<<<24576, 256, 0, stream>>>(Wqkv, wqkvb, 6291456);
  gemm256_kernel<1><<<dim3((QKVN / 256) * (MROWS / 256)), 512, 0, stream>>>(
      xb, wqkvb, (void*)qkvb, MROWS, QKVN, DD, QKVN / 256);
  rope_tables_kernel<<<512, 256, 0, stream>>>(cosT, sinT);
  rope_scatter_kernel<<<40960, 256, 0, stream>>>(qkvb, cosT, sinT, Qb, Kb);
  v_scatter_kernel<<<512, 256, 0, stream>>>(qkvb, Vtb);
  cast_bf16_kernel<<<16384, 256, 0, stream>>>(Wo, wob, 4194304);   // overwrites qkvb (dead)
  flash_attn_kernel<<<512, 256, 0, stream>>>(Qb, Kb, Vtb, attnb);
  gemm256_kernel<0><<<dim3((DD / 256) * (MROWS / 256)), 512, 0, stream>>>(
      attnb, wob, d_out, MROWS, DD, DD, DD / 256);
}

// Round 9
// 724.199 us; speedup vs baseline: 1.3822x; 1.2006x over previous
//
#include <hip/hip_runtime.h>
#include <stdint.h>

// Problem constants
#define BB 2
#define SS 2048
#define DD 4096
#define NH 32
#define NKVH 8
#define HD 128
#define QKVN 6144          // (32 + 2*8) * 128
#define MROWS (BB * SS)    // 4096
#define LOG2E 1.4426950408889634f

typedef short bf16x8 __attribute__((ext_vector_type(8)));   // 8 bf16 in 4 VGPRs
typedef float f32x4 __attribute__((ext_vector_type(4)));

__device__ __forceinline__ short f32_bf16(float f) {
  union { float f; unsigned u; } c; c.f = f;
  unsigned r = (c.u + 0x7fffu + ((c.u >> 16) & 1u)) >> 16;   // RNE
  return (short)r;
}
__device__ __forceinline__ float bf16_f32(short h) {
  union { unsigned u; float f; } c; c.u = ((unsigned)(unsigned short)h) << 16;
  return c.f;
}

// async global->LDS, 16B per lane. LDS dest must be wave-uniform base + lane*16.
__device__ __forceinline__ void async16(const void* g, void* l) {
  __builtin_amdgcn_global_load_lds(
      (const __attribute__((address_space(1))) unsigned int*)(uintptr_t)g,
      (__attribute__((address_space(3))) unsigned int*)(uintptr_t)l,
      16, 0, 0);
}

// ---------------------------------------------------------------- cast f32 -> bf16
__global__ __launch_bounds__(256) void cast_bf16_kernel(const float* __restrict__ in,
                                                        short* __restrict__ out, int n4) {
  int i = blockIdx.x * 256 + threadIdx.x;
  if (i >= n4) return;
  float4 v = ((const float4*)in)[i];
  short4 o;
  o.x = f32_bf16(v.x); o.y = f32_bf16(v.y); o.z = f32_bf16(v.z); o.w = f32_bf16(v.w);
  ((short4*)out)[i] = o;
}

// ---------------------------------------------------------------- rope tables
__global__ __launch_bounds__(256) void rope_tables_kernel(float* __restrict__ cosT,
                                                          float* __restrict__ sinT) {
  int idx = blockIdx.x * 256 + threadIdx.x;   // S*64
  if (idx >= SS * 64) return;
  int s = idx >> 6, t = idx & 63;
  float invf = exp2f(-(float)t * (18.931568569324174f / 64.0f));  // log2(500000)/64
  float fr = (float)s * invf;
  float sv, cv;
  sincosf(fr, &sv, &cv);
  cosT[idx] = cv;
  sinT[idx] = sv;
}

// ---------------------------------------------------------------- rope + scatter (Q,K only)
__global__ __launch_bounds__(256) void rope_scatter_kernel(const short* __restrict__ qkv,
    const float* __restrict__ cosT, const float* __restrict__ sinT,
    short* __restrict__ Qb, short* __restrict__ Kb) {
  int idx = blockIdx.x * 256 + threadIdx.x;   // B*S*40*64
  if (idx >= BB * SS * 40 * 64) return;
  int t = idx & 63;
  int hh = (idx >> 6) % 40;
  int bs = (idx >> 6) / 40;
  int s = bs & (SS - 1);
  int b = bs >> 11;
  const short* row = qkv + (long)bs * QKVN + hh * HD;
  float x1 = bf16_f32(row[t]);
  float x2 = bf16_f32(row[t + 64]);
  float c = cosT[(s << 6) + t], sn = sinT[(s << 6) + t];
  float o1 = x1 * c - x2 * sn;
  float o2 = x2 * c + x1 * sn;
  if (hh < 32) {
    const float sc = 0.08838834764831845f;  // 1/sqrt(128), folded into Q
    o1 *= sc; o2 *= sc;
    short* q = Qb + ((long)(b * NH + hh) * SS + s) * HD;
    q[t] = f32_bf16(o1); q[t + 64] = f32_bf16(o2);
  } else {
    short* k = Kb + ((long)(b * NKVH + (hh - 32)) * SS + s) * HD;
    k[t] = f32_bf16(o1); k[t + 64] = f32_bf16(o2);
  }
}

// ---------------------------------------------------------------- V transpose scatter
__global__ __launch_bounds__(256) void v_scatter_kernel(const short* __restrict__ qkv,
                                                        short* __restrict__ Vtb) {
  int bid = blockIdx.x;                 // 512 = B * NKVH * (SS/64)
  int s0 = (bid & 31) << 6;
  int kvh = (bid >> 5) & 7;
  int b = bid >> 8;
  const short* src = qkv + (long)(b * SS + s0) * QKVN + 5120 + kvh * HD;
  short* dst = Vtb + ((long)(b * NKVH + kvh) * HD) * SS + s0;
  int w = threadIdx.x >> 6, l = threadIdx.x & 63;
#pragma unroll
  for (int it = 0; it < 32; ++it) {
    int d = (it << 2) + w;
    dst[(long)d * SS + l] = src[(long)l * QKVN + d];
  }
}

// ---------------------------------------------------------------- GEMM 256x256 8-phase (T2+T3+T4+T5)
#define STAGE256(kt, bsel)                                                          \
  {                                                                                 \
    const long kbase_ = (long)(kt) << 6;                                            \
    _Pragma("unroll") for (int i_ = 0; i_ < 4; i_++) {                              \
      const int idx_ = tid + i_ * 512;                                              \
      const int row_ = idx_ >> 3, slot_ = idx_ & 7;                                 \
      const int ss_ = slot_ ^ (row_ & 7);                                           \
      async16(Ag0 + (long)row_ * K + kbase_ + ss_ * 8,                              \
              &Abuf[bsel][row_ * 64 + slot_ * 8]);                                  \
      async16(Bg0 + (long)row_ * K + kbase_ + ss_ * 8,                              \
              &Bbuf[bsel][row_ * 64 + slot_ * 8]);                                  \
    }                                                                               \
  }

#define GPHASE(p, LASTP)                                                            \
  {                                                                                 \
    bf16x8 afr[2][2];                                                               \
    _Pragma("unroll") for (int mi = 0; mi < 2; mi++)                                \
      _Pragma("unroll") for (int kk = 0; kk < 2; kk++)                              \
        afr[mi][kk] = *(const bf16x8*)&Ac[(((p) * 2 + mi) * 16 + l16) * 64 +        \
                                          ((((kk << 2) + quad) ^ xr) << 3)];        \
    __builtin_amdgcn_s_barrier();                                                   \
    asm volatile("s_waitcnt lgkmcnt(0)" ::: "memory");                              \
    __builtin_amdgcn_sched_barrier(0);                                              \
    __builtin_amdgcn_s_setprio(1);                                                  \
    _Pragma("unroll") for (int mi = 0; mi < 2; mi++)                                \
      _Pragma("unroll") for (int nr = 0; nr < 4; nr++)                              \
        _Pragma("unroll") for (int kk = 0; kk < 2; kk++)                            \
          acc[(p) * 2 + mi][nr] = __builtin_amdgcn_mfma_f32_16x16x32_bf16(          \
              afr[mi][kk], bfr[nr][kk], acc[(p) * 2 + mi][nr], 0, 0, 0);            \
    __builtin_amdgcn_s_setprio(0);                                                  \
    if (!(LASTP)) __builtin_amdgcn_s_barrier();                                     \
  }

template <int STORE_BF16>
__global__ __launch_bounds__(512) void gemm256_kernel(const short* __restrict__ A,
    const short* __restrict__ B, void* __restrict__ Cv, int M, int N, int K, int gx) {
  __shared__ __align__(16) short Abuf[2][256 * 64];   // 64KB
  __shared__ __align__(16) short Bbuf[2][256 * 64];   // 64KB
  const int tid = threadIdx.x;
  const int lane = tid & 63, wave = tid >> 6;
  const int quad = lane >> 4, l16 = lane & 15;
  const int wm = wave >> 2;          // 0..1: M-half
  const int wn = wave & 3;           // 0..3: N-quarter
  const int xr = l16 & 7;            // read-side XOR key

  const int nwg = gridDim.x;
  const int cpx = nwg >> 3;
  const int wg = ((int)blockIdx.x & 7) * cpx + ((int)blockIdx.x >> 3);
  const int m0 = (wg / gx) << 8;
  const int n0 = (wg % gx) << 8;

  const short* Ag0 = A + (long)m0 * K;
  const short* Bg0 = B + (long)n0 * K;

  f32x4 acc[8][4];
#pragma unroll
  for (int mr = 0; mr < 8; mr++)
#pragma unroll
    for (int nr = 0; nr < 4; nr++) acc[mr][nr] = (f32x4){0.f, 0.f, 0.f, 0.f};

  const int nk = K >> 6;

  STAGE256(0, 0);
  asm volatile("s_waitcnt vmcnt(0)" ::: "memory");
  __builtin_amdgcn_sched_barrier(0);
  __builtin_amdgcn_s_barrier();

  int cur = 0;
#pragma unroll 1
  for (int kt = 0; kt < nk; ++kt) {
    if (kt + 1 < nk) {
      if (cur == 0) { STAGE256(kt + 1, 1); } else { STAGE256(kt + 1, 0); }
    }
    const short* Ac = &Abuf[cur][wm * 128 * 64];
    const short* Bc = &Bbuf[cur][wn * 64 * 64];

    bf16x8 bfr[4][2];
#pragma unroll
    for (int nr = 0; nr < 4; nr++)
#pragma unroll
      for (int kk = 0; kk < 2; kk++)
        bfr[nr][kk] = *(const bf16x8*)&Bc[(nr * 16 + l16) * 64 +
                                          ((((kk << 2) + quad) ^ xr) << 3)];
    GPHASE(0, 0)
    GPHASE(1, 0)
    GPHASE(2, 0)
    GPHASE(3, 1)

    asm volatile("s_waitcnt vmcnt(0)" ::: "memory");
    __builtin_amdgcn_sched_barrier(0);
    __builtin_amdgcn_s_barrier();
    cur ^= 1;
  }

#pragma unroll
  for (int mr = 0; mr < 8; mr++)
#pragma unroll
    for (int nr = 0; nr < 4; nr++)
#pragma unroll
      for (int r = 0; r < 4; r++) {
        long row = m0 + wm * 128 + mr * 16 + quad * 4 + r;
        long col = n0 + wn * 64 + nr * 16 + l16;
        if (STORE_BF16)
          ((short*)Cv)[row * N + col] = f32_bf16(acc[mr][nr][r]);
        else
          ((float*)Cv)[row * N + col] = acc[mr][nr][r];
      }
}

// ---------------------------------------------------------------- flash attention v9
// v9: BLOCK-COOPERATIVE K+V LDS STAGING (4x L2-traffic cut). Cross-round evidence:
// flash pinned at ~260-300us across 5 variants that changed load batching, L2
// residency, and occupancy (2x waves was SLOWER) — the only invariant was each
// wave redundantly streaming full K+V tiles (2048 waves x 33 x 32KB = 2.2GB,
// 13.6 B/cy/CU, 64KB working set thrashing the 32KB L1). Now each block stages
// K[64x128] and V[128x64] ONCE into LDS (557MB total, /4).
// Structure: block = 128 contiguous Q-rows (4 waves x 32), tile-pair (qb,15-qb)
// -> uniform 34 barrier-steps per block (waves idle <=1 step/half; compute
// guarded, barriers unconditional). Counted-vmcnt pipeline (T4): stage K[t+1]
// after post-QK barrier (hides under exp/P/PV), stage V[t+1] after post-PV
// barrier (hides under next QK); top wait vmcnt(4) retires K[t], pre-PV wait
// vmcnt(4) retires V[t] — never 0 mid-loop. Raw s_barrier + per-wave counted
// drains + sched_barrier(0) fencing (v8.1-proven discipline). Q-frag loads
// drained (vmcnt(0)) before prologue so staging counts stay exact. Both tiles
// XOR-swizzled (rule #21: linear dest, pre-swizzled source col, swizzled read).
// LDS 50KB/block -> 2 blocks/CU @ (256,2), VGPR cap 128 (v7-proven live set).
#define PSS 72   // P LDS row stride (elements): 144B, 16B-multiple

#define STAGEK(j0_)                                                                 \
  {                                                                                 \
    _Pragma("unroll") for (int i_ = 0; i_ < 4; i_++) {                              \
      const int idx_ = tid + i_ * 256;                                              \
      const int r_ = idx_ >> 4, s_ = idx_ & 15;                                     \
      async16(Kb + (long)((j0_) + r_) * HD + ((s_ ^ (r_ & 7)) << 3),                \
              &Ks[r_ * 128 + (s_ << 3)]);                                           \
    }                                                                               \
  }

#define STAGEV(j0_)                                                                 \
  {                                                                                 \
    _Pragma("unroll") for (int i_ = 0; i_ < 4; i_++) {                              \
      const int idx_ = tid + i_ * 256;                                              \
      const int r_ = idx_ >> 3, s_ = idx_ & 7;                                      \
      async16(Vb + (long)r_ * SS + (j0_) + ((s_ ^ (r_ & 7)) << 3),                  \
              &Vs[r_ * 64 + (s_ << 3)]);                                            \
    }                                                                               \
  }

__global__ __launch_bounds__(256, 2) void flash_attn_kernel(const short* __restrict__ Q,
    const short* __restrict__ Kt, const short* __restrict__ Vt, short* __restrict__ O) {
  __shared__ __align__(16) short Ks[64 * 128];   // 16KB K tile (swizzled)
  __shared__ __align__(16) short Vs[128 * 64];   // 16KB V tile (swizzled, [d][key])
  __shared__ __align__(16) short Ps[4][32 * PSS];
  const int tid = threadIdx.x;
  const int wave = tid >> 6, lane = tid & 63;
  const int quad = lane >> 4, l16 = lane & 15;
  const int k7 = l16 & 7;                        // read-side XOR key

  // XCD co-location decode: 512 blocks; blocks sharing (b,kvh) share bid%8.
  const int flat = blockIdx.x;
  const int xcd = flat & 7;
  const int kk_ = flat >> 3;          // 0..63
  const int gsel = kk_ >> 5;          // 0..1
  const int jj = kk_ & 31;            // 0..31
  const int g = xcd * 2 + gsel;       // 0..15 = (b,kvh) group
  const int b = g >> 3, kvh = g & 7;
  const int h = (kvh << 2) + (jj >> 3);
  const int qb0 = jj & 7;

  const short* Kb = Kt + (long)(b * NKVH + kvh) * SS * HD;
  const short* Vb = Vt + (long)(b * NKVH + kvh) * HD * SS;
  short* Pw = &Ps[wave][0];

  // Two causal-complementary 128-row block-tiles: steps = (2qb+2)+(32-2qb) = 34.
#pragma unroll 1
  for (int half = 0; half < 2; half++) {
    const int qb = half ? (15 - qb0) : qb0;
    const int q0b = qb << 7;
    const int q0w = q0b + (wave << 5);
    const int nfull = q0w >> 6;            // this wave's last (masked) tile
    const int tsteps = (q0b >> 6) + 2;     // block-uniform step count

    const short* Qw = Q + ((long)(b * NH + h) * SS + q0w) * HD;
    bf16x8 qf[2][4];
#pragma unroll
    for (int i = 0; i < 2; i++)
#pragma unroll
      for (int kk = 0; kk < 4; kk++)
        qf[i][kk] = *(const bf16x8*)&Qw[(i * 16 + l16) * HD + kk * 32 + quad * 8];
    // drain Q loads so staging vmcnt counts stay exact
    asm volatile("s_waitcnt vmcnt(0)" ::: "memory");
    __builtin_amdgcn_sched_barrier(0);

    f32x4 oacc[2][8];
#pragma unroll
    for (int i = 0; i < 2; i++)
#pragma unroll
      for (int jo = 0; jo < 8; jo++) oacc[i][jo] = (f32x4){0.f, 0.f, 0.f, 0.f};
    float l_i[2][4];
#pragma unroll
    for (int i = 0; i < 2; i++)
#pragma unroll
      for (int r = 0; r < 4; r++) l_i[i][r] = 0.f;

    // prologue: stage K[0] then V[0]  (outstanding: K 4 oldest, V 4 newest)
    STAGEK(0)
    STAGEV(0)

#pragma unroll 1
    for (int t = 0; t < tsteps; t++) {
      const int j0 = t << 6;
      const bool active = (t <= nfull);
      const bool havenext = (t + 1 < tsteps);

      // top: retire K[t] (V[t] may still fly), align block
      asm volatile("s_waitcnt vmcnt(4)" ::: "memory");
      __builtin_amdgcn_sched_barrier(0);
      __builtin_amdgcn_s_barrier();
      __builtin_amdgcn_sched_barrier(0);

      f32x4 sc[2][4];
      if (active) {
        // QK from LDS K tile
        bf16x8 kf[16];
#pragma unroll
        for (int kk = 0; kk < 4; kk++)
#pragma unroll
          for (int j = 0; j < 4; j++)
            kf[kk * 4 + j] = *(const bf16x8*)&Ks[(j * 16 + l16) * 128 +
                                                 ((((kk << 2) + quad) ^ k7) << 3)];
#pragma unroll
        for (int i = 0; i < 2; i++)
#pragma unroll
          for (int j = 0; j < 4; j++) sc[i][j] = (f32x4){0.f, 0.f, 0.f, 0.f};
        __builtin_amdgcn_s_setprio(1);
#pragma unroll
        for (int kk = 0; kk < 4; kk++)
#pragma unroll
          for (int i = 0; i < 2; i++)
#pragma unroll
            for (int j = 0; j < 4; j++)
              sc[i][j] = __builtin_amdgcn_mfma_f32_16x16x32_bf16(
                  qf[i][kk], kf[kk * 4 + j], sc[i][j], 0, 0, 0);
        __builtin_amdgcn_s_setprio(0);
      }

      // all waves done reading Ks[t]
      __builtin_amdgcn_s_barrier();
      __builtin_amdgcn_sched_barrier(0);
      if (havenext) STAGEK(j0 + 64)   // hides under exp/P/PV

      if (active) {
        if (t == nfull) {
#pragma unroll
          for (int i = 0; i < 2; i++)
#pragma unroll
            for (int r = 0; r < 4; r++) {
              int row = q0w + i * 16 + quad * 4 + r;
#pragma unroll
              for (int j = 0; j < 4; j++) {
                int col = j0 + j * 16 + l16;
                if (col > row) sc[i][j][r] = -3.0e38f;
              }
            }
        }
        // p = exp(s); per-lane row-sum partials (max-free)
#pragma unroll
        for (int i = 0; i < 2; i++)
#pragma unroll
          for (int r = 0; r < 4; r++) {
            float ps = 0.f;
#pragma unroll
            for (int j = 0; j < 4; j++) {
              float p = __builtin_amdgcn_exp2f(sc[i][j][r] * LOG2E);
              sc[i][j][r] = p;
              ps += p;
            }
            l_i[i][r] += ps;
          }
        // P: C-layout -> per-wave LDS -> A-layout
#pragma unroll
        for (int i = 0; i < 2; i++)
#pragma unroll
          for (int j = 0; j < 4; j++)
#pragma unroll
            for (int r = 0; r < 4; r++)
              Pw[(i * 16 + quad * 4 + r) * PSS + j * 16 + l16] = f32_bf16(sc[i][j][r]);
      }

      // retire V[t] (K[t+1] may still fly), align block
      if (havenext) {
        asm volatile("s_waitcnt vmcnt(4)" ::: "memory");
      } else {
        asm volatile("s_waitcnt vmcnt(0)" ::: "memory");
      }
      __builtin_amdgcn_sched_barrier(0);
      __builtin_amdgcn_s_barrier();
      __builtin_amdgcn_sched_barrier(0);

      if (active) {
        asm volatile("s_waitcnt lgkmcnt(0)" ::: "memory");   // P writes landed
        bf16x8 ap[2][2];
#pragma unroll
        for (int kv = 0; kv < 2; kv++) {
          ap[kv][0] = *(const bf16x8*)&Pw[l16 * PSS + kv * 32 + quad * 8];
          ap[kv][1] = *(const bf16x8*)&Pw[(16 + l16) * PSS + kv * 32 + quad * 8];
        }
        // PV from LDS V tile
        __builtin_amdgcn_s_setprio(1);
#pragma unroll
        for (int jo = 0; jo < 8; jo++) {
          bf16x8 v0 = *(const bf16x8*)&Vs[(jo * 16 + l16) * 64 + ((quad ^ k7) << 3)];
          oacc[0][jo] = __builtin_amdgcn_mfma_f32_16x16x32_bf16(ap[0][0], v0,
                                                                oacc[0][jo], 0, 0, 0);
          oacc[1][jo] = __builtin_amdgcn_mfma_f32_16x16x32_bf16(ap[0][1], v0,
                                                                oacc[1][jo], 0, 0, 0);
        }
#pragma unroll
        for (int jo = 0; jo < 8; jo++) {
          bf16x8 v1 = *(const bf16x8*)&Vs[(jo * 16 + l16) * 64 +
                                          (((4 + quad) ^ k7) << 3)];
          oacc[0][jo] = __builtin_amdgcn_mfma_f32_16x16x32_bf16(ap[1][0], v1,
                                                                oacc[0][jo], 0, 0, 0);
          oacc[1][jo] = __builtin_amdgcn_mfma_f32_16x16x32_bf16(ap[1][1], v1,
                                                                oacc[1][jo], 0, 0, 0);
        }
        __builtin_amdgcn_s_setprio(0);
      }

      // all waves done reading Vs[t]
      __builtin_amdgcn_s_barrier();
      __builtin_amdgcn_sched_barrier(0);
      if (havenext) STAGEV(j0 + 64)   // hides under next QK
    }

    // epilogue: reduce l across the 16 lanes of each quad (once), store
    short* Ob = O + (long)(b * SS + q0w) * DD + h * HD;
#pragma unroll
    for (int i = 0; i < 2; i++)
#pragma unroll
      for (int r = 0; r < 4; r++) {
        float s = l_i[i][r];
        s += __shfl_xor(s, 1, 64);
        s += __shfl_xor(s, 2, 64);
        s += __shfl_xor(s, 4, 64);
        s += __shfl_xor(s, 8, 64);
        float inv = 1.0f / s;
        int row = i * 16 + quad * 4 + r;
#pragma unroll
        for (int jo = 0; jo < 8; jo++)
          Ob[(long)row * DD + jo * 16 + l16] = f32_bf16(oacc[i][jo][r] * inv);
      }
  }
}

// ---------------------------------------------------------------- launch
extern "C" void kernel_launch(void* const* d_in, const int* in_sizes, int n_in,
                              void* d_out, int out_size, void* d_ws, size_t ws_size,
                              hipStream_t stream) {
  (void)in_sizes; (void)n_in; (void)out_size; (void)ws_size;
  const float* x    = (const float*)d_in[0];
  const float* Wqkv = (const float*)d_in[1];
  const float* Wo   = (const float*)d_in[2];
  char* ws = (char*)d_ws;
  short* xb    = (short*)(ws + 0);            // x bf16 (33.5MB); reused as attn out
  short* wqkvb = (short*)(ws + 33554432);     // Wqkv bf16 (50.3MB)
  short* qkvb  = (short*)(ws + 83886080);     // qkv (50.3MB); reused as Wo bf16
  short* Qb    = (short*)(ws + 134217728);    // 33.5MB
  short* Kb    = (short*)(ws + 167772160);    // 8.4MB
  short* Vtb   = (short*)(ws + 176160768);    // 8.4MB
  float* cosT  = (float*)(ws + 184549376);    // 0.5MB
  float* sinT  = (float*)(ws + 185073664);    // 0.5MB
  short* wob   = qkvb;
  short* attnb = xb;

  cast_bf16_kernel<<<16384, 256, 0, stream>>>(x, xb, 4194304);
  cast_bf16_kernel<<<24576, 256, 0, stream>>>(Wqkv, wqkvb, 6291456);
  gemm256_kernel<1><<<dim3((QKVN / 256) * (MROWS / 256)), 512, 0, stream>>>(
      xb, wqkvb, (void*)qkvb, MROWS, QKVN, DD, QKVN / 256);
  rope_tables_kernel<<<512, 256, 0, stream>>>(cosT, sinT);
  rope_scatter_kernel<<<40960, 256, 0, stream>>>(qkvb, cosT, sinT, Qb, Kb);
  v_scatter_kernel<<<512, 256, 0, stream>>>(qkvb, Vtb);
  cast_bf16_kernel<<<16384, 256, 0, stream>>>(Wo, wob, 4194304);   // overwrites qkvb (dead)
  flash_attn_kernel<<<512, 256, 0, stream>>>(Qb, Kb, Vtb, attnb);
  gemm256_kernel<0><<<dim3((DD / 256) * (MROWS / 256)), 512, 0, stream>>>(
      attnb, wob, d_out, MROWS, DD, DD, DD / 256);
}